// Round 1
// baseline (1071.749 us; speedup 1.0000x reference)
//
#include <hip/hip_runtime.h>
#include <cmath>

#define B_ 4
#define M_ 128
#define H_ 1024
#define NH_ 16
#define L_ 1024
#define E_ 64
#define R_ 512
#define EMB_ 768
#define BS_ 64
#define NC_ 97
#define NPAIR_ (B_*R_)   // 2048

// workspace layout (floats)
#define OFF_ENT   0                           // B*E*H      = 262144
#define OFF_ATTN  (OFF_ENT  + B_*E_*H_)       // B*E*NH*L   = 4194304
#define OFF_HT    (OFF_ATTN + B_*E_*NH_*L_)   // NPAIR*L    = 2097152
#define OFF_REL   (OFF_HT   + NPAIR_*L_)      // NPAIR*H    = 2097152
#define OFF_HSF   (OFF_REL  + NPAIR_*H_)      // NPAIR*EMB  = 1572864
#define OFF_TSF   (OFF_HSF  + NPAIR_*EMB_)    // NPAIR*EMB  = 1572864
// total = 11,796,480 floats = 47.2 MB

// ---------------- mention -> entity logsumexp pooling ----------------
__global__ __launch_bounds__(256) void k_ent_pool(const float* __restrict__ ent_lhs,
                                                  const int* __restrict__ labels,
                                                  float* __restrict__ ent_embeds) {
    int blk = blockIdx.x;            // b*E + e
    int b = blk >> 6, e = blk & 63;
    __shared__ int lbl[M_];
    int t = threadIdx.x;
    if (t < M_) lbl[t] = labels[b*M_ + t];
    __syncthreads();
    const float* src = ent_lhs + (size_t)b * M_ * H_;
    float mx[4], sm[4];
    #pragma unroll
    for (int j = 0; j < 4; ++j) { mx[j] = -INFINITY; sm[j] = 0.f; }
    int cnt = 0;
    for (int m = 0; m < M_; ++m) {
        if (lbl[m] != e) continue;
        ++cnt;
        const float* row = src + m * H_;
        #pragma unroll
        for (int j = 0; j < 4; ++j) {
            float x = row[t + j*256];
            if (x > mx[j]) { sm[j] = sm[j] * __expf(mx[j] - x) + 1.f; mx[j] = x; }
            else           { sm[j] += __expf(x - mx[j]); }
        }
    }
    float* dst = ent_embeds + (size_t)blk * H_;
    #pragma unroll
    for (int j = 0; j < 4; ++j)
        dst[t + j*256] = (cnt > 0) ? (mx[j] + __logf(sm[j])) : 0.f;
}

// ---------------- mention -> entity mean of attention ----------------
__global__ __launch_bounds__(256) void k_ent_attn(const float* __restrict__ attn,
                                                  const int* __restrict__ labels,
                                                  float* __restrict__ ent_attn) {
    int blk = blockIdx.x;            // ((b*E+e)*NH + nh)
    int nh = blk & 15, e = (blk >> 4) & 63, b = blk >> 10;
    __shared__ int lbl[M_];
    int t = threadIdx.x;
    if (t < M_) lbl[t] = labels[b*M_ + t];
    __syncthreads();
    const float* src = attn + (size_t)(b*NH_ + nh) * M_ * L_;
    float acc[4] = {0.f, 0.f, 0.f, 0.f};
    int cnt = 0;
    for (int m = 0; m < M_; ++m) {
        if (lbl[m] != e) continue;
        ++cnt;
        const float* row = src + m * L_;
        #pragma unroll
        for (int j = 0; j < 4; ++j) acc[j] += row[t + j*256];
    }
    float inv = 1.f / fmaxf((float)cnt, 1.f);
    float* dst = ent_attn + (size_t)blk * L_;
    #pragma unroll
    for (int j = 0; j < 4; ++j) dst[t + j*256] = acc[j] * inv;
}

// ---------------- per-pair attention product + normalize ----------------
__global__ __launch_bounds__(256) void k_ht(const float* __restrict__ ent_attn,
                                            const int* __restrict__ hts,
                                            float* __restrict__ ht) {
    int blk = blockIdx.x;            // n = b*R + r
    int b = blk >> 9;
    int hidx = hts[blk*2 + 0], tidx = hts[blk*2 + 1];
    const float* ha = ent_attn + (size_t)(b*E_ + hidx) * NH_ * L_;
    const float* ta = ent_attn + (size_t)(b*E_ + tidx) * NH_ * L_;
    int t = threadIdx.x;
    float v[4]; float part = 0.f;
    #pragma unroll
    for (int j = 0; j < 4; ++j) {
        int l = t + j*256;
        float s = 0.f;
        #pragma unroll
        for (int nh = 0; nh < NH_; ++nh)
            s += ha[nh*L_ + l] * ta[nh*L_ + l];
        v[j] = s * (1.f/16.f);
        part += v[j];
    }
    #pragma unroll
    for (int off = 32; off > 0; off >>= 1) part += __shfl_down(part, off);
    __shared__ float wsum[4];
    if ((t & 63) == 0) wsum[t >> 6] = part;
    __syncthreads();
    float tot = wsum[0] + wsum[1] + wsum[2] + wsum[3];
    float scale = 1.f / (tot + 1e-5f);
    float* dst = ht + (size_t)blk * L_;
    #pragma unroll
    for (int j = 0; j < 4; ++j) dst[t + j*256] = v[j] * scale;
}

// ---------------- rel = ht @ seq  (per doc: [R,L]x[L,H]) ----------------
__global__ __launch_bounds__(256) void k_rel(const float* __restrict__ ht,
                                             const float* __restrict__ seq,
                                             float* __restrict__ rel) {
    int b  = blockIdx.z;
    int r0 = blockIdx.y * 64;
    int d0 = blockIdx.x * 64;
    __shared__ float As[16*68];
    __shared__ float Bs[16*64];
    int t = threadIdx.x;
    int tr = t >> 4, tc = t & 15;
    const float* A  = ht  + ((size_t)b*R_ + r0) * L_;
    const float* Bm = seq + (size_t)b * L_ * H_ + d0;
    float acc[4][4] = {};
    for (int k0 = 0; k0 < L_; k0 += 16) {
        int kk = t & 15, rr0 = t >> 4;
        #pragma unroll
        for (int rep = 0; rep < 4; ++rep) {
            int rr = rr0 + rep*16;
            As[kk*68 + rr] = A[(size_t)rr*L_ + k0 + kk];
        }
        int dd = t & 63, ll0 = t >> 6;
        #pragma unroll
        for (int rep = 0; rep < 4; ++rep) {
            int ll = ll0 + rep*4;
            Bs[ll*64 + dd] = Bm[(size_t)(k0+ll)*H_ + dd];
        }
        __syncthreads();
        #pragma unroll
        for (int kk2 = 0; kk2 < 16; ++kk2) {
            float4 a4 = *(const float4*)&As[kk2*68 + tr*4];
            float4 b4 = *(const float4*)&Bs[kk2*64 + tc*4];
            float av[4] = {a4.x, a4.y, a4.z, a4.w};
            float bv[4] = {b4.x, b4.y, b4.z, b4.w};
            #pragma unroll
            for (int i = 0; i < 4; ++i)
                #pragma unroll
                for (int j = 0; j < 4; ++j)
                    acc[i][j] = fmaf(av[i], bv[j], acc[i][j]);
        }
        __syncthreads();
    }
    #pragma unroll
    for (int i = 0; i < 4; ++i) {
        float4 o = make_float4(acc[i][0], acc[i][1], acc[i][2], acc[i][3]);
        *(float4*)&rel[((size_t)b*R_ + r0 + tr*4 + i) * H_ + d0 + tc*4] = o;
    }
}

// ------- extractor: tanh([gather(ent_embeds) | rel] @ W + bias) -------
__global__ __launch_bounds__(256) void k_extract(const float* __restrict__ ent_embeds,
                                                 const float* __restrict__ rel,
                                                 const int* __restrict__ hts,
                                                 const float* __restrict__ W,
                                                 const float* __restrict__ bias,
                                                 float* __restrict__ out,
                                                 int which) {
    int n0 = blockIdx.y * 64;
    int d0 = blockIdx.x * 64;
    __shared__ float As[16*68];
    __shared__ float Bs[16*64];
    __shared__ int rowoff[64];
    int t = threadIdx.x;
    if (t < 64) {
        int n = n0 + t;
        int b = n >> 9;
        int idx = hts[n*2 + which];
        rowoff[t] = (b*E_ + idx) * H_;
    }
    __syncthreads();
    int tr = t >> 4, tc = t & 15;
    float acc[4][4] = {};
    for (int k0 = 0; k0 < 2*H_; k0 += 16) {
        int kk = t & 15, rr0 = t >> 4;
        if (k0 < H_) {
            #pragma unroll
            for (int rep = 0; rep < 4; ++rep) {
                int rr = rr0 + rep*16;
                As[kk*68 + rr] = ent_embeds[(size_t)rowoff[rr] + k0 + kk];
            }
        } else {
            #pragma unroll
            for (int rep = 0; rep < 4; ++rep) {
                int rr = rr0 + rep*16;
                As[kk*68 + rr] = rel[((size_t)(n0+rr))*H_ + (k0 - H_) + kk];
            }
        }
        int dd = t & 63, ll0 = t >> 6;
        #pragma unroll
        for (int rep = 0; rep < 4; ++rep) {
            int ll = ll0 + rep*4;
            Bs[ll*64 + dd] = W[(size_t)(k0+ll)*EMB_ + d0 + dd];
        }
        __syncthreads();
        #pragma unroll
        for (int kk2 = 0; kk2 < 16; ++kk2) {
            float4 a4 = *(const float4*)&As[kk2*68 + tr*4];
            float4 b4 = *(const float4*)&Bs[kk2*64 + tc*4];
            float av[4] = {a4.x, a4.y, a4.z, a4.w};
            float bv[4] = {b4.x, b4.y, b4.z, b4.w};
            #pragma unroll
            for (int i = 0; i < 4; ++i)
                #pragma unroll
                for (int j = 0; j < 4; ++j)
                    acc[i][j] = fmaf(av[i], bv[j], acc[i][j]);
        }
        __syncthreads();
    }
    #pragma unroll
    for (int i = 0; i < 4; ++i) {
        int n = n0 + tr*4 + i;
        float4 o;
        o.x = tanhf(acc[i][0] + bias[d0 + tc*4 + 0]);
        o.y = tanhf(acc[i][1] + bias[d0 + tc*4 + 1]);
        o.z = tanhf(acc[i][2] + bias[d0 + tc*4 + 2]);
        o.w = tanhf(acc[i][3] + bias[d0 + tc*4 + 3]);
        *(float4*)&out[(size_t)n*EMB_ + d0 + tc*4] = o;
    }
}

// ---------------- classifier: init logits with bias ----------------
__global__ void k_init_out(const float* __restrict__ bb, float* __restrict__ out) {
    int idx = blockIdx.x*256 + threadIdx.x;
    if (idx < NPAIR_*NC_) out[idx] = bb[idx % NC_];
}

// ------- classifier: logits += sum_q (hs[n,i]*ts[n,j]) * Wb[q,c] -------
// split-K over the 12 blocks (blockIdx.x = k), n-tile 64 (blockIdx.y)
__global__ __launch_bounds__(256) void k_cls(const float* __restrict__ hsf,
                                             const float* __restrict__ tsf,
                                             const float* __restrict__ Wb,
                                             float* __restrict__ out) {
    int kblk = blockIdx.x;           // 0..11
    int n0   = blockIdx.y * 64;
    __shared__ float hs_s[64*68];    // [i][nn]
    __shared__ float ts_s[64*68];    // [j][nn]
    __shared__ float wb_s[64*100];   // [j][c]
    int t = threadIdx.x;
    {
        int i = t & 63, nn0 = t >> 6;
        #pragma unroll
        for (int rep = 0; rep < 16; ++rep) {
            int nn = nn0 + rep*4;
            hs_s[i*68 + nn] = hsf[(size_t)(n0+nn)*EMB_ + kblk*64 + i];
            ts_s[i*68 + nn] = tsf[(size_t)(n0+nn)*EMB_ + kblk*64 + i];
        }
    }
    int tr = t >> 4, tc = t & 15;
    float acc[4][7] = {};
    const size_t kbase = (size_t)kblk * 4096 * NC_;
    // register prefetch of the i=0 Wb slab (6208 floats / block)
    float wreg[25];
    #pragma unroll
    for (int u = 0; u < 25; ++u) {
        int idx = t + u*256;
        wreg[u] = (idx < 64*NC_) ? Wb[kbase + idx] : 0.f;
    }
    for (int i = 0; i < 64; ++i) {
        __syncthreads();             // prev compute done (i==0: hs/ts staged)
        #pragma unroll
        for (int u = 0; u < 25; ++u) {
            int idx = t + u*256;
            if (idx < 64*NC_) {
                int j = idx / NC_;
                int c = idx - j*NC_;
                wb_s[j*100 + c] = wreg[u];
            }
        }
        __syncthreads();
        if (i < 63) {                // prefetch next slab; hides under compute
            const float* g = Wb + kbase + (size_t)(i+1)*64*NC_;
            #pragma unroll
            for (int u = 0; u < 25; ++u) {
                int idx = t + u*256;
                wreg[u] = (idx < 64*NC_) ? g[idx] : 0.f;
            }
        }
        float4 h4 = *(const float4*)&hs_s[i*68 + tr*4];
        #pragma unroll 4
        for (int j = 0; j < 64; ++j) {
            float4 t4 = *(const float4*)&ts_s[j*68 + tr*4];
            float m0 = h4.x*t4.x, m1 = h4.y*t4.y, m2 = h4.z*t4.z, m3 = h4.w*t4.w;
            const float* wrow = &wb_s[j*100 + tc*6];
            #pragma unroll
            for (int cc = 0; cc < 7; ++cc) {
                float w = wrow[cc];
                acc[0][cc] = fmaf(m0, w, acc[0][cc]);
                acc[1][cc] = fmaf(m1, w, acc[1][cc]);
                acc[2][cc] = fmaf(m2, w, acc[2][cc]);
                acc[3][cc] = fmaf(m3, w, acc[3][cc]);
            }
        }
    }
    #pragma unroll
    for (int nn = 0; nn < 4; ++nn) {
        int n = n0 + tr*4 + nn;
        #pragma unroll
        for (int cc = 0; cc < 7; ++cc) {
            int c = tc*6 + cc;
            if (cc < 6 || tc == 15)   // c ranges overlap by design; write once
                atomicAdd(&out[(size_t)n*NC_ + c], acc[nn][cc]);
        }
    }
}

extern "C" void kernel_launch(void* const* d_in, const int* in_sizes, int n_in,
                              void* d_out, int out_size, void* d_ws, size_t ws_size,
                              hipStream_t stream) {
    (void)in_sizes; (void)n_in; (void)out_size; (void)ws_size;
    const float* seq  = (const float*)d_in[0];
    const float* ent  = (const float*)d_in[1];
    const float* attn = (const float*)d_in[2];
    const int*   lbl  = (const int*)d_in[3];
    const int*   hts  = (const int*)d_in[4];
    const float* Wh   = (const float*)d_in[5];
    const float* bh   = (const float*)d_in[6];
    const float* Wt   = (const float*)d_in[7];
    const float* bt   = (const float*)d_in[8];
    const float* Wb   = (const float*)d_in[9];
    const float* bb   = (const float*)d_in[10];
    float* out = (float*)d_out;
    float* ws  = (float*)d_ws;

    float* ent_embeds = ws + OFF_ENT;
    float* ent_attn   = ws + OFF_ATTN;
    float* ht         = ws + OFF_HT;
    float* rel        = ws + OFF_REL;
    float* hsf        = ws + OFF_HSF;
    float* tsf        = ws + OFF_TSF;

    k_ent_pool<<<B_*E_, 256, 0, stream>>>(ent, lbl, ent_embeds);
    k_ent_attn<<<B_*E_*NH_, 256, 0, stream>>>(attn, lbl, ent_attn);
    k_ht<<<NPAIR_, 256, 0, stream>>>(ent_attn, hts, ht);
    k_rel<<<dim3(H_/64, R_/64, B_), 256, 0, stream>>>(ht, seq, rel);
    k_extract<<<dim3(EMB_/64, NPAIR_/64), 256, 0, stream>>>(ent_embeds, rel, hts, Wh, bh, hsf, 0);
    k_extract<<<dim3(EMB_/64, NPAIR_/64), 256, 0, stream>>>(ent_embeds, rel, hts, Wt, bt, tsf, 1);
    k_init_out<<<(NPAIR_*NC_ + 255)/256, 256, 0, stream>>>(bb, out);
    k_cls<<<dim3(12, NPAIR_/64), 256, 0, stream>>>(hsf, tsf, Wb, out);
}

// Round 2
// 384.337 us; speedup vs baseline: 2.7886x; 2.7886x over previous
//
#include <hip/hip_runtime.h>
#include <cmath>

#define B_ 4
#define M_ 128
#define H_ 1024
#define NH_ 16
#define L_ 1024
#define E_ 64
#define R_ 512
#define EMB_ 768
#define BS_ 64
#define NC_ 97
#define NPAIR_ (B_*R_)   // 2048

typedef _Float16 half8 __attribute__((ext_vector_type(8)));
typedef float f32x4 __attribute__((ext_vector_type(4)));

// workspace layout (float offsets). Total = 11,796,480 floats = 47.19 MB (same as R0).
#define OFF_ENT   0                            // 262144
#define OFF_ATTN  (OFF_ENT  + B_*E_*H_)        // 4194304 floats; Wbt (2752512 fl) aliases here after k_ht
#define OFF_HT    (OFF_ATTN + B_*E_*NH_*L_)
#define OFF_REL   (OFF_HT   + NPAIR_*L_)
#define OFF_HSF   (OFF_REL  + NPAIR_*H_)       // half[2048][768] = 786432 floats
#define OFF_TSF   (OFF_HSF  + NPAIR_*EMB_/2)
#define OFF_WHT   (OFF_TSF  + NPAIR_*EMB_/2)   // half[768][2048]
#define OFF_WTT   (OFF_WHT  + EMB_*2*H_/2)

__device__ __forceinline__ void gload_lds16(const void* g, void* l) {
    __builtin_amdgcn_global_load_lds(
        (const __attribute__((address_space(1))) unsigned int*)g,
        (__attribute__((address_space(3))) unsigned int*)l, 16, 0, 0);
}

// ---------------- mention -> entity logsumexp pooling (unchanged) ----------------
__global__ __launch_bounds__(256) void k_ent_pool(const float* __restrict__ ent_lhs,
                                                  const int* __restrict__ labels,
                                                  float* __restrict__ ent_embeds) {
    int blk = blockIdx.x;
    int b = blk >> 6, e = blk & 63;
    __shared__ int lbl[M_];
    int t = threadIdx.x;
    if (t < M_) lbl[t] = labels[b*M_ + t];
    __syncthreads();
    const float* src = ent_lhs + (size_t)b * M_ * H_;
    float mx[4], sm[4];
    #pragma unroll
    for (int j = 0; j < 4; ++j) { mx[j] = -INFINITY; sm[j] = 0.f; }
    int cnt = 0;
    for (int m = 0; m < M_; ++m) {
        if (lbl[m] != e) continue;
        ++cnt;
        const float* row = src + m * H_;
        #pragma unroll
        for (int j = 0; j < 4; ++j) {
            float x = row[t + j*256];
            if (x > mx[j]) { sm[j] = sm[j] * __expf(mx[j] - x) + 1.f; mx[j] = x; }
            else           { sm[j] += __expf(x - mx[j]); }
        }
    }
    float* dst = ent_embeds + (size_t)blk * H_;
    #pragma unroll
    for (int j = 0; j < 4; ++j)
        dst[t + j*256] = (cnt > 0) ? (mx[j] + __logf(sm[j])) : 0.f;
}

// ---------------- mention -> entity mean of attention (unchanged) ----------------
__global__ __launch_bounds__(256) void k_ent_attn(const float* __restrict__ attn,
                                                  const int* __restrict__ labels,
                                                  float* __restrict__ ent_attn) {
    int blk = blockIdx.x;
    int nh = blk & 15, e = (blk >> 4) & 63, b = blk >> 10;
    __shared__ int lbl[M_];
    int t = threadIdx.x;
    if (t < M_) lbl[t] = labels[b*M_ + t];
    __syncthreads();
    const float* src = attn + (size_t)(b*NH_ + nh) * M_ * L_;
    float acc[4] = {0.f, 0.f, 0.f, 0.f};
    int cnt = 0;
    for (int m = 0; m < M_; ++m) {
        if (lbl[m] != e) continue;
        ++cnt;
        const float* row = src + m * L_;
        #pragma unroll
        for (int j = 0; j < 4; ++j) acc[j] += row[t + j*256];
    }
    float inv = 1.f / fmaxf((float)cnt, 1.f);
    float* dst = ent_attn + (size_t)blk * L_;
    #pragma unroll
    for (int j = 0; j < 4; ++j) dst[t + j*256] = acc[j] * inv;
}

// ---------------- per-pair attention product + normalize (unchanged) ----------------
__global__ __launch_bounds__(256) void k_ht(const float* __restrict__ ent_attn,
                                            const int* __restrict__ hts,
                                            float* __restrict__ ht) {
    int blk = blockIdx.x;
    int b = blk >> 9;
    int hidx = hts[blk*2 + 0], tidx = hts[blk*2 + 1];
    const float* ha = ent_attn + (size_t)(b*E_ + hidx) * NH_ * L_;
    const float* ta = ent_attn + (size_t)(b*E_ + tidx) * NH_ * L_;
    int t = threadIdx.x;
    float v[4]; float part = 0.f;
    #pragma unroll
    for (int j = 0; j < 4; ++j) {
        int l = t + j*256;
        float s = 0.f;
        #pragma unroll
        for (int nh = 0; nh < NH_; ++nh)
            s += ha[nh*L_ + l] * ta[nh*L_ + l];
        v[j] = s * (1.f/16.f);
        part += v[j];
    }
    #pragma unroll
    for (int off = 32; off > 0; off >>= 1) part += __shfl_down(part, off);
    __shared__ float wsum[4];
    if ((t & 63) == 0) wsum[t >> 6] = part;
    __syncthreads();
    float tot = wsum[0] + wsum[1] + wsum[2] + wsum[3];
    float scale = 1.f / (tot + 1e-5f);
    float* dst = ht + (size_t)blk * L_;
    #pragma unroll
    for (int j = 0; j < 4; ++j) dst[t + j*256] = v[j] * scale;
}

// ---------------- rel = ht @ seq  (fp32, unchanged this round) ----------------
__global__ __launch_bounds__(256) void k_rel(const float* __restrict__ ht,
                                             const float* __restrict__ seq,
                                             float* __restrict__ rel) {
    int b  = blockIdx.z;
    int r0 = blockIdx.y * 64;
    int d0 = blockIdx.x * 64;
    __shared__ float As[16*68];
    __shared__ float Bs[16*64];
    int t = threadIdx.x;
    int tr = t >> 4, tc = t & 15;
    const float* A  = ht  + ((size_t)b*R_ + r0) * L_;
    const float* Bm = seq + (size_t)b * L_ * H_ + d0;
    float acc[4][4] = {};
    for (int k0 = 0; k0 < L_; k0 += 16) {
        int kk = t & 15, rr0 = t >> 4;
        #pragma unroll
        for (int rep = 0; rep < 4; ++rep) {
            int rr = rr0 + rep*16;
            As[kk*68 + rr] = A[(size_t)rr*L_ + k0 + kk];
        }
        int dd = t & 63, ll0 = t >> 6;
        #pragma unroll
        for (int rep = 0; rep < 4; ++rep) {
            int ll = ll0 + rep*4;
            Bs[ll*64 + dd] = Bm[(size_t)(k0+ll)*H_ + dd];
        }
        __syncthreads();
        #pragma unroll
        for (int kk2 = 0; kk2 < 16; ++kk2) {
            float4 a4 = *(const float4*)&As[kk2*68 + tr*4];
            float4 b4 = *(const float4*)&Bs[kk2*64 + tc*4];
            float av[4] = {a4.x, a4.y, a4.z, a4.w};
            float bv[4] = {b4.x, b4.y, b4.z, b4.w};
            #pragma unroll
            for (int i = 0; i < 4; ++i)
                #pragma unroll
                for (int j = 0; j < 4; ++j)
                    acc[i][j] = fmaf(av[i], bv[j], acc[i][j]);
        }
        __syncthreads();
    }
    #pragma unroll
    for (int i = 0; i < 4; ++i) {
        float4 o = make_float4(acc[i][0], acc[i][1], acc[i][2], acc[i][3]);
        *(float4*)&rel[((size_t)b*R_ + r0 + tr*4 + i) * H_ + d0 + tc*4] = o;
    }
}

// ---------------- prep: W[2048][768] fp32 -> WT[768][2048] half ----------------
__global__ __launch_bounds__(256) void k_prep_wt(const float* __restrict__ W,
                                                 _Float16* __restrict__ WT) {
    int k0 = blockIdx.x * 64;    // 32 tiles
    int d0 = blockIdx.y * 64;    // 12 tiles
    __shared__ float s[64*65];
    int t = threadIdx.x;
    #pragma unroll
    for (int u = 0; u < 16; ++u) {
        int idx = t + u*256; int rr = idx >> 6, cc = idx & 63;
        s[rr*65 + cc] = W[(size_t)(k0+rr)*EMB_ + d0 + cc];
    }
    __syncthreads();
    #pragma unroll
    for (int u = 0; u < 16; ++u) {
        int idx = t + u*256; int dd = idx >> 6, kk = idx & 63;
        WT[(size_t)(d0+dd)*2048 + k0 + kk] = (_Float16)s[kk*65 + dd];
    }
}

// --------- prep: Wb[49152][97] fp32 -> Wbt[768 slices][112 c][64 j] half ---------
__global__ __launch_bounds__(256) void k_prep_wbt(const float* __restrict__ Wb,
                                                  _Float16* __restrict__ Wbt) {
    int kbi = blockIdx.x;         // 0..767
    __shared__ float s[64*97];    // rows j (64), cols c (97), contiguous copy
    int t = threadIdx.x;
    size_t gbase = (size_t)kbi * 64 * NC_;
    #pragma unroll
    for (int u = 0; u < 25; ++u) {
        int idx = t + u*256;
        if (idx < 64*NC_) s[idx] = Wb[gbase + idx];   // s[j*97+c]
    }
    __syncthreads();
    _Float16* dst = Wbt + (size_t)kbi * 112*64;
    #pragma unroll
    for (int u = 0; u < 28; ++u) {
        int idx = t + u*256;              // 7168 = 28*256
        int c = idx >> 6, j = idx & 63;
        float v = (c < NC_) ? s[j*NC_ + c] : 0.f;
        dst[idx] = (_Float16)v;
    }
}

// ------- extractor (MFMA): outh = half( tanh([gather(ent)|rel] @ W + b) ) -------
__global__ __launch_bounds__(256) void k_extract_mfma(const float* __restrict__ ent_embeds,
                                                      const float* __restrict__ rel,
                                                      const int* __restrict__ hts,
                                                      const _Float16* __restrict__ WT,
                                                      const float* __restrict__ bias,
                                                      _Float16* __restrict__ outh,
                                                      int which) {
    const int d0 = blockIdx.x * 64;      // 12
    const int n0 = blockIdx.y * 64;      // 32
    __shared__ _Float16 wt_s[2][64*64];  // [d-row][k-unit], XOR-swizzled units
    const int t = threadIdx.x;
    const int w = t >> 6, lane = t & 63;
    const int r = lane & 15, g = lane >> 4;
    const int row8 = lane >> 3, u8 = lane & 7;
    const int swz_w = (u8 ^ row8) * 8;   // swizzled global unit offset (halfs) for staging

    // per-lane A row pointers
    const int nrow = n0 + w*16 + r;
    const int hidx = hts[nrow*2 + which];
    const float* entp = ent_embeds + ((size_t)((nrow >> 9)*E_ + hidx))*H_;
    const float* relp = rel + (size_t)nrow * H_;

    // stage chunk 0 of WT, prefetch A chunk 0
    #pragma unroll
    for (int c2 = w*2; c2 < w*2+2; ++c2)
        gload_lds16(WT + (size_t)(d0 + c2*8 + row8)*2048 + 0*64 + swz_w,
                    &wt_s[0][c2*512]);
    float4 nA0 = *(const float4*)(entp + g*8);
    float4 nA1 = *(const float4*)(entp + g*8 + 4);
    float4 nB0 = *(const float4*)(entp + 32 + g*8);
    float4 nB1 = *(const float4*)(entp + 32 + g*8 + 4);

    f32x4 acc[4] = {};
    __syncthreads();

    for (int c = 0; c < 32; ++c) {
        const int cur = c & 1;
        if (c < 31) {
            // stage next WT chunk (async; drains at end-of-iter barrier)
            const int k0n = (c+1)*64;
            #pragma unroll
            for (int c2 = w*2; c2 < w*2+2; ++c2)
                gload_lds16(WT + (size_t)(d0 + c2*8 + row8)*2048 + k0n + swz_w,
                            &wt_s[cur^1][c2*512]);
        }
        // rotate A prefetch
        float4 cA0 = nA0, cA1 = nA1, cB0 = nB0, cB1 = nB1;
        if (c < 31) {
            const int k0n = (c+1)*64;
            const float* ar = (k0n < 1024) ? (entp + k0n) : (relp + k0n - 1024);
            nA0 = *(const float4*)(ar + g*8);
            nA1 = *(const float4*)(ar + g*8 + 4);
            nB0 = *(const float4*)(ar + 32 + g*8);
            nB1 = *(const float4*)(ar + 32 + g*8 + 4);
        }
        half8 aF0 = { (_Float16)cA0.x, (_Float16)cA0.y, (_Float16)cA0.z, (_Float16)cA0.w,
                      (_Float16)cA1.x, (_Float16)cA1.y, (_Float16)cA1.z, (_Float16)cA1.w };
        half8 aF1 = { (_Float16)cB0.x, (_Float16)cB0.y, (_Float16)cB0.z, (_Float16)cB0.w,
                      (_Float16)cB1.x, (_Float16)cB1.y, (_Float16)cB1.z, (_Float16)cB1.w };
        #pragma unroll
        for (int df = 0; df < 4; ++df) {
            half8 b0 = *(const half8*)&wt_s[cur][(df*16 + r)*64 + ((g ^ (r&7))*8)];
            acc[df] = __builtin_amdgcn_mfma_f32_16x16x32_f16(aF0, b0, acc[df], 0, 0, 0);
            half8 b1 = *(const half8*)&wt_s[cur][(df*16 + r)*64 + (((4+g) ^ (r&7))*8)];
            acc[df] = __builtin_amdgcn_mfma_f32_16x16x32_f16(aF1, b1, acc[df], 0, 0, 0);
        }
        __syncthreads();
    }
    // epilogue: bias + tanh, store half. D layout: m = g*4+reg, n(col d) = r
    #pragma unroll
    for (int df = 0; df < 4; ++df) {
        float bv = bias[d0 + df*16 + r];
        #pragma unroll
        for (int q2 = 0; q2 < 4; ++q2) {
            float v = tanhf(acc[df][q2] + bv);
            outh[(size_t)(n0 + w*16 + g*4 + q2)*EMB_ + d0 + df*16 + r] = (_Float16)v;
        }
    }
}

// ---------------- classifier: init logits with bias ----------------
__global__ void k_init_out(const float* __restrict__ bb, float* __restrict__ out) {
    int idx = blockIdx.x*256 + threadIdx.x;
    if (idx < NPAIR_*NC_) out[idx] = bb[idx % NC_];
}

// ------- classifier (MFMA): out[n,c] += sum_{i,j} hs[n,i] ts[n,j] Wbt[i][c][j] -------
__global__ __launch_bounds__(256) void k_cls_mfma(const _Float16* __restrict__ hsf,
                                                  const _Float16* __restrict__ tsf,
                                                  const _Float16* __restrict__ Wbt,
                                                  float* __restrict__ out) {
    const int kb2 = blockIdx.x;          // 0..23: kb (12) x i-half (2)
    const int kb = kb2 >> 1, ih = kb2 & 1;
    const int n0 = blockIdx.y * 64;      // 32 n-tiles
    __shared__ _Float16 ts_s[64*72];     // [n][j] pad 72
    __shared__ _Float16 hs_s[64*40];     // [n][ii] pad 40 (ii in 0..31)
    __shared__ _Float16 wb_s[2][112*64]; // dbuf, [c-row][j-unit] swizzled
    const int t = threadIdx.x;
    const int w = t >> 6, lane = t & 63;
    const int r = lane & 15, g = lane >> 4;
    const int row8 = lane >> 3, u8 = lane & 7;
    const int swz_w = (u8 ^ row8) * 8;

    // stage ts_s (64 j of this kb), hs_s (32 i of this kb-half)
    {
        int n = t & 63, q = t >> 6;
        const half8 tv0 = *(const half8*)&tsf[(size_t)(n0+n)*EMB_ + kb*64 + q*16];
        const half8 tv1 = *(const half8*)&tsf[(size_t)(n0+n)*EMB_ + kb*64 + q*16 + 8];
        *(half8*)&ts_s[n*72 + q*16]     = tv0;
        *(half8*)&ts_s[n*72 + q*16 + 8] = tv1;
        const half8 hv = *(const half8*)&hsf[(size_t)(n0+n)*EMB_ + kb*64 + ih*32 + q*8];
        *(half8*)&hs_s[n*40 + q*8] = hv;
    }
    const _Float16* wsrc = Wbt + (size_t)(kb*64 + ih*32) * 7168;
    // stage wb slice 0 (14 x 1KB wave-calls, wave w takes c%4==w)
    for (int c = w; c < 14; c += 4)
        gload_lds16(wsrc + (c*8 + row8)*64 + swz_w, &wb_s[0][c*512]);

    __syncthreads();

    // per-wave ts fragments (constant over i): lane holds ts[w*16+r][j0h*32 + g*8 .. +7]
    const half8 tsF0 = *(const half8*)&ts_s[(w*16 + r)*72 + g*8];
    const half8 tsF1 = *(const half8*)&ts_s[(w*16 + r)*72 + 32 + g*8];

    f32x4 acc[7] = {};
    for (int i = 0; i < 32; ++i) {
        const int cur = i & 1;
        if (i < 31) {
            const _Float16* sp = wsrc + (size_t)(i+1) * 7168;
            for (int c = w; c < 14; c += 4)
                gload_lds16(sp + (c*8 + row8)*64 + swz_w, &wb_s[cur^1][c*512]);
        }
        _Float16 h = hs_s[(w*16 + r)*40 + i];
        half8 a0, a1;
        #pragma unroll
        for (int e = 0; e < 8; ++e) { a0[e] = tsF0[e] * h; a1[e] = tsF1[e] * h; }
        #pragma unroll
        for (int cf = 0; cf < 7; ++cf) {
            half8 b0 = *(const half8*)&wb_s[cur][(cf*16 + r)*64 + ((g ^ (r&7))*8)];
            acc[cf] = __builtin_amdgcn_mfma_f32_16x16x32_f16(a0, b0, acc[cf], 0, 0, 0);
            half8 b1 = *(const half8*)&wb_s[cur][(cf*16 + r)*64 + (((4+g) ^ (r&7))*8)];
            acc[cf] = __builtin_amdgcn_mfma_f32_16x16x32_f16(a1, b1, acc[cf], 0, 0, 0);
        }
        __syncthreads();
    }
    // epilogue: D m = g*4+reg (pair row), n = r (class col); mask c<97
    #pragma unroll
    for (int cf = 0; cf < 7; ++cf) {
        int c = cf*16 + r;
        #pragma unroll
        for (int q2 = 0; q2 < 4; ++q2) {
            if (cf < 6 || r == 0)
                atomicAdd(&out[(size_t)(n0 + w*16 + g*4 + q2)*NC_ + c], acc[cf][q2]);
        }
    }
}

extern "C" void kernel_launch(void* const* d_in, const int* in_sizes, int n_in,
                              void* d_out, int out_size, void* d_ws, size_t ws_size,
                              hipStream_t stream) {
    (void)in_sizes; (void)n_in; (void)out_size; (void)ws_size;
    const float* seq  = (const float*)d_in[0];
    const float* ent  = (const float*)d_in[1];
    const float* attn = (const float*)d_in[2];
    const int*   lbl  = (const int*)d_in[3];
    const int*   hts  = (const int*)d_in[4];
    const float* Wh   = (const float*)d_in[5];
    const float* bh   = (const float*)d_in[6];
    const float* Wt   = (const float*)d_in[7];
    const float* bt   = (const float*)d_in[8];
    const float* Wb   = (const float*)d_in[9];
    const float* bb   = (const float*)d_in[10];
    float* out = (float*)d_out;
    float* ws  = (float*)d_ws;

    float* ent_embeds = ws + OFF_ENT;
    float* ent_attn   = ws + OFF_ATTN;
    float* ht         = ws + OFF_HT;
    float* rel        = ws + OFF_REL;
    _Float16* hsf = (_Float16*)(ws + OFF_HSF);
    _Float16* tsf = (_Float16*)(ws + OFF_TSF);
    _Float16* WhT = (_Float16*)(ws + OFF_WHT);
    _Float16* WtT = (_Float16*)(ws + OFF_WTT);
    _Float16* Wbt = (_Float16*)(ws + OFF_ATTN);   // aliases attn region (dead after k_ht)

    k_prep_wt<<<dim3(32, 12), 256, 0, stream>>>(Wh, WhT);
    k_prep_wt<<<dim3(32, 12), 256, 0, stream>>>(Wt, WtT);
    k_ent_pool<<<B_*E_, 256, 0, stream>>>(ent, lbl, ent_embeds);
    k_ent_attn<<<B_*E_*NH_, 256, 0, stream>>>(attn, lbl, ent_attn);
    k_ht<<<NPAIR_, 256, 0, stream>>>(ent_attn, hts, ht);
    k_prep_wbt<<<768, 256, 0, stream>>>(Wb, Wbt);   // after k_ht: attn region now dead
    k_rel<<<dim3(H_/64, R_/64, B_), 256, 0, stream>>>(ht, seq, rel);
    k_extract_mfma<<<dim3(12, 32), 256, 0, stream>>>(ent_embeds, rel, hts, WhT, bh, hsf, 0);
    k_extract_mfma<<<dim3(12, 32), 256, 0, stream>>>(ent_embeds, rel, hts, WtT, bt, tsf, 1);
    k_init_out<<<(NPAIR_*NC_ + 255)/256, 256, 0, stream>>>(bb, out);
    k_cls_mfma<<<dim3(24, 32), 256, 0, stream>>>(hsf, tsf, Wbt, out);
}

// Round 3
// 302.301 us; speedup vs baseline: 3.5453x; 1.2714x over previous
//
#include <hip/hip_runtime.h>
#include <cmath>

#define B_ 4
#define M_ 128
#define H_ 1024
#define NH_ 16
#define L_ 1024
#define E_ 64
#define R_ 512
#define EMB_ 768
#define BS_ 64
#define NC_ 97
#define NPAIR_ (B_*R_)   // 2048
#define LC_ 16           // l-chunk in k_ht

typedef _Float16 half8 __attribute__((ext_vector_type(8)));
typedef float f32x4 __attribute__((ext_vector_type(4)));

// ---------------- workspace layout (float offsets), total 9,701,376 fl = 38.8 MB ----------------
#define OFF_ENT    0                            // ent_embeds fp32            262144
#define OFF_ATTNH  262144                       // ent_attn_t half [4][64][1024][16]  (2097152 fl)
#define OFF_VH     2359296                      // vh half [2048][1024]       (1048576 fl)
// Wbt (half, 2752512 fl) aliases [OFF_ATTNH, OFF_ATTNH+2752512) = attn_t + part of vh,
// written only AFTER k_ht and k_rel have consumed both.
#define OFF_S      3407872                      // s fp32 [2048]
#define OFF_SEQT   3409920                      // seqT half [4][1024][1024]  (2097152 fl)
#define OFF_RELH   5507072                      // relh half [2048][1024]     (1048576 fl)
#define OFF_HSF    6555648                      // hsf half [2048][768]       (786432 fl)
#define OFF_TSF    7342080
#define OFF_WHT    8128512                      // WhT half [768][2048]       (786432 fl)
#define OFF_WTT    8914944

__device__ __forceinline__ void gload_lds16(const void* g, void* l) {
    __builtin_amdgcn_global_load_lds(
        (const __attribute__((address_space(1))) unsigned int*)g,
        (__attribute__((address_space(3))) unsigned int*)l, 16, 0, 0);
}

// ---------------- mention -> entity logsumexp pooling ----------------
__global__ __launch_bounds__(256) void k_ent_pool(const float* __restrict__ ent_lhs,
                                                  const int* __restrict__ labels,
                                                  float* __restrict__ ent_embeds) {
    int blk = blockIdx.x;
    int b = blk >> 6, e = blk & 63;
    __shared__ int lbl[M_];
    int t = threadIdx.x;
    if (t < M_) lbl[t] = labels[b*M_ + t];
    __syncthreads();
    const float* src = ent_lhs + (size_t)b * M_ * H_;
    float mx[4], sm[4];
    #pragma unroll
    for (int j = 0; j < 4; ++j) { mx[j] = -INFINITY; sm[j] = 0.f; }
    int cnt = 0;
    for (int m = 0; m < M_; ++m) {
        if (lbl[m] != e) continue;
        ++cnt;
        const float* row = src + m * H_;
        #pragma unroll
        for (int j = 0; j < 4; ++j) {
            float x = row[t + j*256];
            if (x > mx[j]) { sm[j] = sm[j] * __expf(mx[j] - x) + 1.f; mx[j] = x; }
            else           { sm[j] += __expf(x - mx[j]); }
        }
    }
    float* dst = ent_embeds + (size_t)blk * H_;
    #pragma unroll
    for (int j = 0; j < 4; ++j)
        dst[t + j*256] = (cnt > 0) ? (mx[j] + __logf(sm[j])) : 0.f;
}

// ------- mention -> entity mean attention, TRANSPOSED half output [b][e][l][nh] -------
__global__ __launch_bounds__(256) void k_ent_attn(const float* __restrict__ attn,
                                                  const int* __restrict__ labels,
                                                  _Float16* __restrict__ ea_t) {
    int blk = blockIdx.x;            // b*64 + e
    int b = blk >> 6, e = blk & 63;
    __shared__ int lbl[M_];
    int t = threadIdx.x;
    if (t < M_) lbl[t] = labels[b*M_ + t];
    __syncthreads();
    const float* src = attn + (size_t)b * NH_ * M_ * L_;
    float acc[16][4] = {};
    int cnt = 0;
    for (int m = 0; m < M_; ++m) {
        if (lbl[m] != e) continue;
        ++cnt;
        const float* mp = src + (size_t)m * L_ + t*4;
        #pragma unroll
        for (int nh = 0; nh < 16; ++nh) {
            float4 v = *(const float4*)(mp + (size_t)nh * M_ * L_);
            acc[nh][0] += v.x; acc[nh][1] += v.y; acc[nh][2] += v.z; acc[nh][3] += v.w;
        }
    }
    float inv = 1.f / fmaxf((float)cnt, 1.f);
    _Float16* dst = ea_t + (size_t)blk * L_ * 16;
    #pragma unroll
    for (int j = 0; j < 4; ++j) {
        int l = t*4 + j;
        half8 o0, o1;
        #pragma unroll
        for (int nh = 0; nh < 8; ++nh) { o0[nh] = (_Float16)(acc[nh][j]*inv); o1[nh] = (_Float16)(acc[nh+8][j]*inv); }
        *(half8*)(dst + (size_t)l*16)     = o0;
        *(half8*)(dst + (size_t)l*16 + 8) = o1;
    }
}

// ------- per-pair attn product, LDS-tiled: vh[n][l] = sum_nh ha*ta (unnormalized) -------
__global__ __launch_bounds__(256) void k_ht(const _Float16* __restrict__ ea_t,
                                            const int* __restrict__ hts,
                                            _Float16* __restrict__ vh) {
    int blk = blockIdx.x;            // b*64 + lc   (256 blocks)
    int b = blk >> 6, lc = blk & 63;
    int l0 = lc * LC_;
    __shared__ _Float16 tile[64*256];   // [e][swz(l)*16 + nh], 32 KB
    int t = threadIdx.x;
    {   // load 64 e-rows x 16 l x 16 nh, XOR-swizzle l by e
        int e = t >> 2, part = t & 3;
        const _Float16* src = ea_t + ((size_t)(b*64 + e)*L_ + l0) * 16;
        #pragma unroll
        for (int u = 0; u < 8; ++u) {
            int unit = part*8 + u;          // 0..31
            int l = unit >> 1, nhh = unit & 1;
            half8 v = *(const half8*)(src + l*16 + nhh*8);
            *(half8*)&tile[e*256 + ((l ^ (e & 15))*16) + nhh*8] = v;
        }
    }
    __syncthreads();
    const int* hp = hts + b * R_ * 2;
    #pragma unroll
    for (int pp = 0; pp < 2; ++pp) {
        int p = pp*256 + t;
        int he = hp[p*2], te = hp[p*2 + 1];
        const _Float16* ha = &tile[he*256];
        const _Float16* ta = &tile[te*256];
        float accl[LC_];
        #pragma unroll
        for (int l = 0; l < LC_; ++l) {
            half8 h0 = *(const half8*)&ha[((l ^ (he & 15))*16)];
            half8 h1 = *(const half8*)&ha[((l ^ (he & 15))*16) + 8];
            half8 t0 = *(const half8*)&ta[((l ^ (te & 15))*16)];
            half8 t1 = *(const half8*)&ta[((l ^ (te & 15))*16) + 8];
            float s = 0.f;
            #pragma unroll
            for (int q = 0; q < 8; ++q)
                s += (float)h0[q]*(float)t0[q] + (float)h1[q]*(float)t1[q];
            accl[l] = s;
        }
        half8 o0, o1;
        #pragma unroll
        for (int q = 0; q < 8; ++q) { o0[q] = (_Float16)accl[q]; o1[q] = (_Float16)accl[q+8]; }
        _Float16* dst = vh + (size_t)(b*R_ + p)*L_ + l0;
        *(half8*)dst = o0;
        *(half8*)(dst + 8) = o1;
    }
}

// ---------------- row sums s[n] = sum_l vh[n][l] ----------------
__global__ __launch_bounds__(256) void k_rowsum(const _Float16* __restrict__ vh,
                                                float* __restrict__ s) {
    int row = blockIdx.x*4 + (threadIdx.x >> 6);
    int lane = threadIdx.x & 63;
    const _Float16* r = vh + (size_t)row * L_;
    float acc = 0.f;
    #pragma unroll
    for (int u = 0; u < 2; ++u) {
        half8 v = *(const half8*)(r + (lane + u*64)*8);
        #pragma unroll
        for (int q = 0; q < 8; ++q) acc += (float)v[q];
    }
    #pragma unroll
    for (int off = 32; off > 0; off >>= 1) acc += __shfl_down(acc, off);
    if (lane == 0) s[row] = acc;
}

// ---------------- prep: seq [b][l][d] fp32 -> seqT [b][d][l] half ----------------
__global__ __launch_bounds__(256) void k_prep_seqt(const float* __restrict__ seq,
                                                   _Float16* __restrict__ seqT) {
    int l0 = blockIdx.x*64, d0 = blockIdx.y*64, b = blockIdx.z;
    __shared__ _Float16 sl[64*72];
    int t = threadIdx.x;
    int lr = t >> 4, dc = (t & 15)*4;
    #pragma unroll
    for (int u = 0; u < 4; ++u) {
        int l = lr + u*16;
        float4 v = *(const float4*)(seq + ((size_t)(b*L_ + l0 + l))*H_ + d0 + dc);
        sl[l*72 + dc+0] = (_Float16)v.x; sl[l*72 + dc+1] = (_Float16)v.y;
        sl[l*72 + dc+2] = (_Float16)v.z; sl[l*72 + dc+3] = (_Float16)v.w;
    }
    __syncthreads();
    int d = t >> 2, lo = (t & 3)*16;
    half8 o0, o1;
    #pragma unroll
    for (int q = 0; q < 8; ++q) { o0[q] = sl[(lo+q)*72 + d]; o1[q] = sl[(lo+8+q)*72 + d]; }
    _Float16* dst = seqT + ((size_t)(b*H_ + d0 + d))*L_ + l0 + lo;
    *(half8*)dst = o0;
    *(half8*)(dst + 8) = o1;
}

// ---------------- prep: W[2048][768] fp32 -> WT[768][2048] half ----------------
__global__ __launch_bounds__(256) void k_prep_wt(const float* __restrict__ W,
                                                 _Float16* __restrict__ WT) {
    int k0 = blockIdx.x * 64;
    int d0 = blockIdx.y * 64;
    __shared__ float s[64*65];
    int t = threadIdx.x;
    #pragma unroll
    for (int u = 0; u < 16; ++u) {
        int idx = t + u*256; int rr = idx >> 6, cc = idx & 63;
        s[rr*65 + cc] = W[(size_t)(k0+rr)*EMB_ + d0 + cc];
    }
    __syncthreads();
    #pragma unroll
    for (int u = 0; u < 16; ++u) {
        int idx = t + u*256; int dd = idx >> 6, kk = idx & 63;
        WT[(size_t)(d0+dd)*2048 + k0 + kk] = (_Float16)s[kk*65 + dd];
    }
}

// --------- prep: Wb[49152][97] fp32 -> Wbt[768 slices][112 c][64 j] half ---------
__global__ __launch_bounds__(256) void k_prep_wbt(const float* __restrict__ Wb,
                                                  _Float16* __restrict__ Wbt) {
    int kbi = blockIdx.x;
    __shared__ float s[64*97];
    int t = threadIdx.x;
    size_t gbase = (size_t)kbi * 64 * NC_;
    #pragma unroll
    for (int u = 0; u < 25; ++u) {
        int idx = t + u*256;
        if (idx < 64*NC_) s[idx] = Wb[gbase + idx];
    }
    __syncthreads();
    _Float16* dst = Wbt + (size_t)kbi * 112*64;
    #pragma unroll
    for (int u = 0; u < 28; ++u) {
        int idx = t + u*256;
        int c = idx >> 6, j = idx & 63;
        float v = (c < NC_) ? s[j*NC_ + c] : 0.f;
        dst[idx] = (_Float16)v;
    }
}

// ------- rel (MFMA): relh[n][d] = (1/(s[n]+1.6e-4)) * sum_l vh[n][l] seqT[b][d][l] -------
__global__ __launch_bounds__(256) void k_rel_mfma(const _Float16* __restrict__ vh,
                                                  const _Float16* __restrict__ seqT,
                                                  const float* __restrict__ s,
                                                  _Float16* __restrict__ relh) {
    const int d0 = blockIdx.x * 64;   // 16
    const int n0 = blockIdx.y * 64;   // 32
    const int b  = n0 >> 9;
    __shared__ _Float16 bs[2][64*64];
    const int t = threadIdx.x;
    const int w = t >> 6, lane = t & 63;
    const int r = lane & 15, g = lane >> 4;
    const int row8 = lane >> 3, u8 = lane & 7;
    const int swz_w = (u8 ^ row8) * 8;

    const _Float16* bsrc = seqT + ((size_t)(b*H_) + d0) * L_;
    #pragma unroll
    for (int c2 = w*2; c2 < w*2+2; ++c2)
        gload_lds16(bsrc + (size_t)(c2*8 + row8)*L_ + swz_w, &bs[0][c2*512]);

    const _Float16* ap = vh + (size_t)(n0 + w*16 + r) * L_;
    half8 nA0 = *(const half8*)(ap + g*8);
    half8 nA1 = *(const half8*)(ap + 32 + g*8);

    f32x4 acc[4] = {};
    __syncthreads();

    for (int c = 0; c < 16; ++c) {
        const int cur = c & 1;
        if (c < 15) {
            const int k0n = (c+1)*64;
            #pragma unroll
            for (int c2 = w*2; c2 < w*2+2; ++c2)
                gload_lds16(bsrc + (size_t)(c2*8 + row8)*L_ + k0n + swz_w, &bs[cur^1][c2*512]);
        }
        half8 cA0 = nA0, cA1 = nA1;
        if (c < 15) {
            const int k0n = (c+1)*64;
            nA0 = *(const half8*)(ap + k0n + g*8);
            nA1 = *(const half8*)(ap + k0n + 32 + g*8);
        }
        #pragma unroll
        for (int df = 0; df < 4; ++df) {
            half8 b0 = *(const half8*)&bs[cur][(df*16 + r)*64 + ((g ^ (r&7))*8)];
            acc[df] = __builtin_amdgcn_mfma_f32_16x16x32_f16(cA0, b0, acc[df], 0, 0, 0);
            half8 b1 = *(const half8*)&bs[cur][(df*16 + r)*64 + (((4+g) ^ (r&7))*8)];
            acc[df] = __builtin_amdgcn_mfma_f32_16x16x32_f16(cA1, b1, acc[df], 0, 0, 0);
        }
        __syncthreads();
    }
    const int nb = n0 + w*16 + g*4;
    float invs[4];
    #pragma unroll
    for (int q = 0; q < 4; ++q) invs[q] = 1.f / (s[nb + q] + 1.6e-4f);
    #pragma unroll
    for (int df = 0; df < 4; ++df)
        #pragma unroll
        for (int q = 0; q < 4; ++q)
            relh[(size_t)(nb + q)*H_ + d0 + df*16 + r] = (_Float16)(acc[df][q] * invs[q]);
}

// ------- extractor (MFMA): outh = half( tanh([gather(ent fp32)|relh] @ W + b) ) -------
__global__ __launch_bounds__(256) void k_extract_mfma(const float* __restrict__ ent_embeds,
                                                      const _Float16* __restrict__ relh,
                                                      const int* __restrict__ hts,
                                                      const _Float16* __restrict__ WhT,
                                                      const _Float16* __restrict__ WtT,
                                                      const float* __restrict__ bh,
                                                      const float* __restrict__ bt,
                                                      _Float16* __restrict__ hsf,
                                                      _Float16* __restrict__ tsf) {
    const int which = blockIdx.z;
    const _Float16* WT = which ? WtT : WhT;
    const float* bias  = which ? bt : bh;
    _Float16* outh     = which ? tsf : hsf;

    const int d0 = blockIdx.x * 64;      // 12
    const int n0 = blockIdx.y * 64;      // 32
    __shared__ _Float16 wt_s[2][64*64];
    const int t = threadIdx.x;
    const int w = t >> 6, lane = t & 63;
    const int r = lane & 15, g = lane >> 4;
    const int row8 = lane >> 3, u8 = lane & 7;
    const int swz_w = (u8 ^ row8) * 8;

    const int nrow = n0 + w*16 + r;
    const int hidx = hts[nrow*2 + which];
    const float* entp = ent_embeds + ((size_t)((nrow >> 9)*E_ + hidx))*H_;
    const _Float16* relp = relh + (size_t)nrow * H_;

    #pragma unroll
    for (int c2 = w*2; c2 < w*2+2; ++c2)
        gload_lds16(WT + (size_t)(d0 + c2*8 + row8)*2048 + swz_w, &wt_s[0][c2*512]);

    // prefetch chunk 0 (fp32 ent)
    float4 nF0 = *(const float4*)(entp + g*8);
    float4 nF1 = *(const float4*)(entp + g*8 + 4);
    float4 nF2 = *(const float4*)(entp + 32 + g*8);
    float4 nF3 = *(const float4*)(entp + 32 + g*8 + 4);
    half8 nH0 = {}, nH1 = {};

    f32x4 acc[4] = {};
    __syncthreads();

    for (int c = 0; c < 32; ++c) {
        const int cur = c & 1;
        if (c < 31) {
            const int k0n = (c+1)*64;
            #pragma unroll
            for (int c2 = w*2; c2 < w*2+2; ++c2)
                gload_lds16(WT + (size_t)(d0 + c2*8 + row8)*2048 + k0n + swz_w,
                            &wt_s[cur^1][c2*512]);
        }
        // materialize current A fragments
        half8 aF0, aF1;
        if (c < 16) {
            aF0 = half8{ (_Float16)nF0.x, (_Float16)nF0.y, (_Float16)nF0.z, (_Float16)nF0.w,
                         (_Float16)nF1.x, (_Float16)nF1.y, (_Float16)nF1.z, (_Float16)nF1.w };
            aF1 = half8{ (_Float16)nF2.x, (_Float16)nF2.y, (_Float16)nF2.z, (_Float16)nF2.w,
                         (_Float16)nF3.x, (_Float16)nF3.y, (_Float16)nF3.z, (_Float16)nF3.w };
        } else {
            aF0 = nH0; aF1 = nH1;
        }
        // prefetch next A chunk
        if (c < 31) {
            const int k0n = (c+1)*64;
            if (k0n < 1024) {
                const float* ar = entp + k0n;
                nF0 = *(const float4*)(ar + g*8);
                nF1 = *(const float4*)(ar + g*8 + 4);
                nF2 = *(const float4*)(ar + 32 + g*8);
                nF3 = *(const float4*)(ar + 32 + g*8 + 4);
            } else {
                const _Float16* ar = relp + (k0n - 1024);
                nH0 = *(const half8*)(ar + g*8);
                nH1 = *(const half8*)(ar + 32 + g*8);
            }
        }
        #pragma unroll
        for (int df = 0; df < 4; ++df) {
            half8 b0 = *(const half8*)&wt_s[cur][(df*16 + r)*64 + ((g ^ (r&7))*8)];
            acc[df] = __builtin_amdgcn_mfma_f32_16x16x32_f16(aF0, b0, acc[df], 0, 0, 0);
            half8 b1 = *(const half8*)&wt_s[cur][(df*16 + r)*64 + (((4+g) ^ (r&7))*8)];
            acc[df] = __builtin_amdgcn_mfma_f32_16x16x32_f16(aF1, b1, acc[df], 0, 0, 0);
        }
        __syncthreads();
    }
    #pragma unroll
    for (int df = 0; df < 4; ++df) {
        float bv = bias[d0 + df*16 + r];
        #pragma unroll
        for (int q2 = 0; q2 < 4; ++q2) {
            float v = tanhf(acc[df][q2] + bv);
            outh[(size_t)(n0 + w*16 + g*4 + q2)*EMB_ + d0 + df*16 + r] = (_Float16)v;
        }
    }
}

// ---------------- classifier: init logits with bias ----------------
__global__ void k_init_out(const float* __restrict__ bb, float* __restrict__ out) {
    int idx = blockIdx.x*256 + threadIdx.x;
    if (idx < NPAIR_*NC_) out[idx] = bb[idx % NC_];
}

// ------- classifier (MFMA): out[n,c] += sum_{i,j} hs[n,i] ts[n,j] Wbt[i][c][j] -------
__global__ __launch_bounds__(256) void k_cls_mfma(const _Float16* __restrict__ hsf,
                                                  const _Float16* __restrict__ tsf,
                                                  const _Float16* __restrict__ Wbt,
                                                  float* __restrict__ out) {
    const int kb2 = blockIdx.x;          // 0..23
    const int kb = kb2 >> 1, ih = kb2 & 1;
    const int n0 = blockIdx.y * 64;
    __shared__ _Float16 ts_s[64*72];
    __shared__ _Float16 hs_s[64*40];
    __shared__ _Float16 wb_s[2][112*64];
    const int t = threadIdx.x;
    const int w = t >> 6, lane = t & 63;
    const int r = lane & 15, g = lane >> 4;
    const int row8 = lane >> 3, u8 = lane & 7;
    const int swz_w = (u8 ^ row8) * 8;

    {
        int n = t & 63, q = t >> 6;
        const half8 tv0 = *(const half8*)&tsf[(size_t)(n0+n)*EMB_ + kb*64 + q*16];
        const half8 tv1 = *(const half8*)&tsf[(size_t)(n0+n)*EMB_ + kb*64 + q*16 + 8];
        *(half8*)&ts_s[n*72 + q*16]     = tv0;
        *(half8*)&ts_s[n*72 + q*16 + 8] = tv1;
        const half8 hv = *(const half8*)&hsf[(size_t)(n0+n)*EMB_ + kb*64 + ih*32 + q*8];
        *(half8*)&hs_s[n*40 + q*8] = hv;
    }
    const _Float16* wsrc = Wbt + (size_t)(kb*64 + ih*32) * 7168;
    for (int c = w; c < 14; c += 4)
        gload_lds16(wsrc + (c*8 + row8)*64 + swz_w, &wb_s[0][c*512]);

    __syncthreads();

    const half8 tsF0 = *(const half8*)&ts_s[(w*16 + r)*72 + g*8];
    const half8 tsF1 = *(const half8*)&ts_s[(w*16 + r)*72 + 32 + g*8];

    f32x4 acc[7] = {};
    for (int i = 0; i < 32; ++i) {
        const int cur = i & 1;
        if (i < 31) {
            const _Float16* sp = wsrc + (size_t)(i+1) * 7168;
            for (int c = w; c < 14; c += 4)
                gload_lds16(sp + (c*8 + row8)*64 + swz_w, &wb_s[cur^1][c*512]);
        }
        _Float16 h = hs_s[(w*16 + r)*40 + i];
        half8 a0, a1;
        #pragma unroll
        for (int e = 0; e < 8; ++e) { a0[e] = tsF0[e] * h; a1[e] = tsF1[e] * h; }
        #pragma unroll
        for (int cf = 0; cf < 7; ++cf) {
            half8 b0 = *(const half8*)&wb_s[cur][(cf*16 + r)*64 + ((g ^ (r&7))*8)];
            acc[cf] = __builtin_amdgcn_mfma_f32_16x16x32_f16(a0, b0, acc[cf], 0, 0, 0);
            half8 b1 = *(const half8*)&wb_s[cur][(cf*16 + r)*64 + (((4+g) ^ (r&7))*8)];
            acc[cf] = __builtin_amdgcn_mfma_f32_16x16x32_f16(a1, b1, acc[cf], 0, 0, 0);
        }
        __syncthreads();
    }
    #pragma unroll
    for (int cf = 0; cf < 7; ++cf) {
        int c = cf*16 + r;
        #pragma unroll
        for (int q2 = 0; q2 < 4; ++q2) {
            if (cf < 6 || r == 0)
                atomicAdd(&out[(size_t)(n0 + w*16 + g*4 + q2)*NC_ + c], acc[cf][q2]);
        }
    }
}

extern "C" void kernel_launch(void* const* d_in, const int* in_sizes, int n_in,
                              void* d_out, int out_size, void* d_ws, size_t ws_size,
                              hipStream_t stream) {
    (void)in_sizes; (void)n_in; (void)out_size; (void)ws_size;
    const float* seq  = (const float*)d_in[0];
    const float* ent  = (const float*)d_in[1];
    const float* attn = (const float*)d_in[2];
    const int*   lbl  = (const int*)d_in[3];
    const int*   hts  = (const int*)d_in[4];
    const float* Wh   = (const float*)d_in[5];
    const float* bh   = (const float*)d_in[6];
    const float* Wt   = (const float*)d_in[7];
    const float* bt   = (const float*)d_in[8];
    const float* Wb   = (const float*)d_in[9];
    const float* bb   = (const float*)d_in[10];
    float* out = (float*)d_out;
    float* ws  = (float*)d_ws;

    float*    ent_embeds = ws + OFF_ENT;
    _Float16* ea_t = (_Float16*)(ws + OFF_ATTNH);
    _Float16* vh   = (_Float16*)(ws + OFF_VH);
    float*    sv   = ws + OFF_S;
    _Float16* seqT = (_Float16*)(ws + OFF_SEQT);
    _Float16* relh = (_Float16*)(ws + OFF_RELH);
    _Float16* hsf  = (_Float16*)(ws + OFF_HSF);
    _Float16* tsf  = (_Float16*)(ws + OFF_TSF);
    _Float16* WhT  = (_Float16*)(ws + OFF_WHT);
    _Float16* WtT  = (_Float16*)(ws + OFF_WTT);
    _Float16* Wbt  = (_Float16*)(ws + OFF_ATTNH);  // aliases ea_t+vh; written after k_rel

    k_prep_seqt<<<dim3(16, 16, 4), 256, 0, stream>>>(seq, seqT);
    k_prep_wt<<<dim3(32, 12), 256, 0, stream>>>(Wh, WhT);
    k_prep_wt<<<dim3(32, 12), 256, 0, stream>>>(Wt, WtT);
    k_ent_pool<<<B_*E_, 256, 0, stream>>>(ent, lbl, ent_embeds);
    k_ent_attn<<<B_*E_, 256, 0, stream>>>(attn, lbl, ea_t);
    k_ht<<<B_*64, 256, 0, stream>>>(ea_t, hts, vh);
    k_rowsum<<<NPAIR_/4, 256, 0, stream>>>(vh, sv);
    k_rel_mfma<<<dim3(16, 32), 256, 0, stream>>>(vh, seqT, sv, relh);
    k_prep_wbt<<<768, 256, 0, stream>>>(Wb, Wbt);   // after k_ht + k_rel: alias region dead
    k_extract_mfma<<<dim3(12, 32, 2), 256, 0, stream>>>(ent_embeds, relh, hts, WhT, WtT, bh, bt, hsf, tsf);
    k_init_out<<<(NPAIR_*NC_ + 255)/256, 256, 0, stream>>>(bb, out);
    k_cls_mfma<<<dim3(24, 32), 256, 0, stream>>>(hsf, tsf, Wbt, out);
}

// Round 4
// 292.564 us; speedup vs baseline: 3.6633x; 1.0333x over previous
//
#include <hip/hip_runtime.h>
#include <cmath>

#define B_ 4
#define M_ 128
#define H_ 1024
#define NH_ 16
#define L_ 1024
#define E_ 64
#define R_ 512
#define EMB_ 768
#define BS_ 64
#define NC_ 97
#define NPAIR_ (B_*R_)   // 2048
#define LC_ 16           // l-chunk in k_ht

typedef _Float16 half8 __attribute__((ext_vector_type(8)));
typedef float f32x4 __attribute__((ext_vector_type(4)));

// ---------------- workspace layout (float offsets), total 9,701,376 fl = 38.8 MB ----------------
#define OFF_ENT    0                            // ent_embeds fp32            262144
#define OFF_ATTNH  262144                       // ent_attn_t half [4][64][1024][16]  (2097152 fl)
#define OFF_VH     2359296                      // vh half [2048][1024]       (1048576 fl)
// Wbt half [768][128][64] = 6291456 halfs = 3145728 fl aliases [OFF_ATTNH, OFF_S) exactly
// (= ea_t + vh), written only AFTER k_ht / k_rowsum / k_rel_mfma consumed both.
#define OFF_S      3407872                      // s fp32 [2048]
#define OFF_SEQT   3409920                      // seqT half [4][1024][1024]  (2097152 fl)
#define OFF_RELH   5507072                      // relh half [2048][1024]     (1048576 fl)
// partial fp32 [12][2048][128] = 3145728 fl aliases [OFF_SEQT, OFF_HSF) exactly
// (= seqT + relh), written by k_cls only AFTER k_extract consumed relh.
#define OFF_HSF    6555648                      // hsf half [2048][768]       (786432 fl)
#define OFF_TSF    7342080
#define OFF_WHT    8128512                      // WhT half [768][2048]       (786432 fl)
#define OFF_WTT    8914944

__device__ __forceinline__ void gload_lds16(const void* g, void* l) {
    __builtin_amdgcn_global_load_lds(
        (const __attribute__((address_space(1))) unsigned int*)g,
        (__attribute__((address_space(3))) unsigned int*)l, 16, 0, 0);
}

// ---------------- mention -> entity logsumexp pooling ----------------
__global__ __launch_bounds__(256) void k_ent_pool(const float* __restrict__ ent_lhs,
                                                  const int* __restrict__ labels,
                                                  float* __restrict__ ent_embeds) {
    int blk = blockIdx.x;
    int b = blk >> 6, e = blk & 63;
    __shared__ int lbl[M_];
    int t = threadIdx.x;
    if (t < M_) lbl[t] = labels[b*M_ + t];
    __syncthreads();
    const float* src = ent_lhs + (size_t)b * M_ * H_;
    float mx[4], sm[4];
    #pragma unroll
    for (int j = 0; j < 4; ++j) { mx[j] = -INFINITY; sm[j] = 0.f; }
    int cnt = 0;
    for (int m = 0; m < M_; ++m) {
        if (lbl[m] != e) continue;
        ++cnt;
        const float* row = src + m * H_;
        #pragma unroll
        for (int j = 0; j < 4; ++j) {
            float x = row[t + j*256];
            if (x > mx[j]) { sm[j] = sm[j] * __expf(mx[j] - x) + 1.f; mx[j] = x; }
            else           { sm[j] += __expf(x - mx[j]); }
        }
    }
    float* dst = ent_embeds + (size_t)blk * H_;
    #pragma unroll
    for (int j = 0; j < 4; ++j)
        dst[t + j*256] = (cnt > 0) ? (mx[j] + __logf(sm[j])) : 0.f;
}

// ------- mention -> entity mean attention, TRANSPOSED half output [b][e][l][nh] -------
__global__ __launch_bounds__(256) void k_ent_attn(const float* __restrict__ attn,
                                                  const int* __restrict__ labels,
                                                  _Float16* __restrict__ ea_t) {
    int blk = blockIdx.x;            // b*64 + e
    int b = blk >> 6, e = blk & 63;
    __shared__ int lbl[M_];
    int t = threadIdx.x;
    if (t < M_) lbl[t] = labels[b*M_ + t];
    __syncthreads();
    const float* src = attn + (size_t)b * NH_ * M_ * L_;
    float acc[16][4] = {};
    int cnt = 0;
    for (int m = 0; m < M_; ++m) {
        if (lbl[m] != e) continue;
        ++cnt;
        const float* mp = src + (size_t)m * L_ + t*4;
        #pragma unroll
        for (int nh = 0; nh < 16; ++nh) {
            float4 v = *(const float4*)(mp + (size_t)nh * M_ * L_);
            acc[nh][0] += v.x; acc[nh][1] += v.y; acc[nh][2] += v.z; acc[nh][3] += v.w;
        }
    }
    float inv = 1.f / fmaxf((float)cnt, 1.f);
    _Float16* dst = ea_t + (size_t)blk * L_ * 16;
    #pragma unroll
    for (int j = 0; j < 4; ++j) {
        int l = t*4 + j;
        half8 o0, o1;
        #pragma unroll
        for (int nh = 0; nh < 8; ++nh) { o0[nh] = (_Float16)(acc[nh][j]*inv); o1[nh] = (_Float16)(acc[nh+8][j]*inv); }
        *(half8*)(dst + (size_t)l*16)     = o0;
        *(half8*)(dst + (size_t)l*16 + 8) = o1;
    }
}

// ------- per-pair attn product, LDS-tiled: vh[n][l] = sum_nh ha*ta (unnormalized) -------
__global__ __launch_bounds__(256) void k_ht(const _Float16* __restrict__ ea_t,
                                            const int* __restrict__ hts,
                                            _Float16* __restrict__ vh) {
    int blk = blockIdx.x;            // b*64 + lc   (256 blocks)
    int b = blk >> 6, lc = blk & 63;
    int l0 = lc * LC_;
    __shared__ _Float16 tile[64*256];   // [e][swz(l)*16 + nh], 32 KB
    int t = threadIdx.x;
    {   // load 64 e-rows x 16 l x 16 nh, XOR-swizzle l by e
        int e = t >> 2, part = t & 3;
        const _Float16* src = ea_t + ((size_t)(b*64 + e)*L_ + l0) * 16;
        #pragma unroll
        for (int u = 0; u < 8; ++u) {
            int unit = part*8 + u;          // 0..31
            int l = unit >> 1, nhh = unit & 1;
            half8 v = *(const half8*)(src + l*16 + nhh*8);
            *(half8*)&tile[e*256 + ((l ^ (e & 15))*16) + nhh*8] = v;
        }
    }
    __syncthreads();
    const int* hp = hts + b * R_ * 2;
    #pragma unroll
    for (int pp = 0; pp < 2; ++pp) {
        int p = pp*256 + t;
        int he = hp[p*2], te = hp[p*2 + 1];
        const _Float16* ha = &tile[he*256];
        const _Float16* ta = &tile[te*256];
        float accl[LC_];
        #pragma unroll
        for (int l = 0; l < LC_; ++l) {
            half8 h0 = *(const half8*)&ha[((l ^ (he & 15))*16)];
            half8 h1 = *(const half8*)&ha[((l ^ (he & 15))*16) + 8];
            half8 t0 = *(const half8*)&ta[((l ^ (te & 15))*16)];
            half8 t1 = *(const half8*)&ta[((l ^ (te & 15))*16) + 8];
            float s = 0.f;
            #pragma unroll
            for (int q = 0; q < 8; ++q)
                s += (float)h0[q]*(float)t0[q] + (float)h1[q]*(float)t1[q];
            accl[l] = s;
        }
        half8 o0, o1;
        #pragma unroll
        for (int q = 0; q < 8; ++q) { o0[q] = (_Float16)accl[q]; o1[q] = (_Float16)accl[q+8]; }
        _Float16* dst = vh + (size_t)(b*R_ + p)*L_ + l0;
        *(half8*)dst = o0;
        *(half8*)(dst + 8) = o1;
    }
}

// ---------------- row sums s[n] = sum_l vh[n][l] ----------------
__global__ __launch_bounds__(256) void k_rowsum(const _Float16* __restrict__ vh,
                                                float* __restrict__ s) {
    int row = blockIdx.x*4 + (threadIdx.x >> 6);
    int lane = threadIdx.x & 63;
    const _Float16* r = vh + (size_t)row * L_;
    float acc = 0.f;
    #pragma unroll
    for (int u = 0; u < 2; ++u) {
        half8 v = *(const half8*)(r + (lane + u*64)*8);
        #pragma unroll
        for (int q = 0; q < 8; ++q) acc += (float)v[q];
    }
    #pragma unroll
    for (int off = 32; off > 0; off >>= 1) acc += __shfl_down(acc, off);
    if (lane == 0) s[row] = acc;
}

// ---------------- prep: seq [b][l][d] fp32 -> seqT [b][d][l] half ----------------
__global__ __launch_bounds__(256) void k_prep_seqt(const float* __restrict__ seq,
                                                   _Float16* __restrict__ seqT) {
    int l0 = blockIdx.x*64, d0 = blockIdx.y*64, b = blockIdx.z;
    __shared__ _Float16 sl[64*72];
    int t = threadIdx.x;
    int lr = t >> 4, dc = (t & 15)*4;
    #pragma unroll
    for (int u = 0; u < 4; ++u) {
        int l = lr + u*16;
        float4 v = *(const float4*)(seq + ((size_t)(b*L_ + l0 + l))*H_ + d0 + dc);
        sl[l*72 + dc+0] = (_Float16)v.x; sl[l*72 + dc+1] = (_Float16)v.y;
        sl[l*72 + dc+2] = (_Float16)v.z; sl[l*72 + dc+3] = (_Float16)v.w;
    }
    __syncthreads();
    int d = t >> 2, lo = (t & 3)*16;
    half8 o0, o1;
    #pragma unroll
    for (int q = 0; q < 8; ++q) { o0[q] = sl[(lo+q)*72 + d]; o1[q] = sl[(lo+8+q)*72 + d]; }
    _Float16* dst = seqT + ((size_t)(b*H_ + d0 + d))*L_ + l0 + lo;
    *(half8*)dst = o0;
    *(half8*)(dst + 8) = o1;
}

// ---------------- prep: W[2048][768] fp32 -> WT[768][2048] half ----------------
__global__ __launch_bounds__(256) void k_prep_wt(const float* __restrict__ W,
                                                 _Float16* __restrict__ WT) {
    int k0 = blockIdx.x * 64;
    int d0 = blockIdx.y * 64;
    __shared__ float s[64*65];
    int t = threadIdx.x;
    #pragma unroll
    for (int u = 0; u < 16; ++u) {
        int idx = t + u*256; int rr = idx >> 6, cc = idx & 63;
        s[rr*65 + cc] = W[(size_t)(k0+rr)*EMB_ + d0 + cc];
    }
    __syncthreads();
    #pragma unroll
    for (int u = 0; u < 16; ++u) {
        int idx = t + u*256; int dd = idx >> 6, kk = idx & 63;
        WT[(size_t)(d0+dd)*2048 + k0 + kk] = (_Float16)s[kk*65 + dd];
    }
}

// --------- prep: Wb[49152][97] fp32 -> Wbt[768 slices][128 c][64 j] half (c padded) ---------
__global__ __launch_bounds__(256) void k_prep_wbt(const float* __restrict__ Wb,
                                                  _Float16* __restrict__ Wbt) {
    int kbi = blockIdx.x;
    __shared__ float s[64*97];
    int t = threadIdx.x;
    size_t gbase = (size_t)kbi * 64 * NC_;
    #pragma unroll
    for (int u = 0; u < 25; ++u) {
        int idx = t + u*256;
        if (idx < 64*NC_) s[idx] = Wb[gbase + idx];   // s[j*97+c]
    }
    __syncthreads();
    _Float16* dst = Wbt + (size_t)kbi * 8192;         // [c 128][j 64]
    #pragma unroll
    for (int u = 0; u < 32; ++u) {
        int idx = t + u*256;
        int c = idx >> 6, j = idx & 63;
        float v = (c < NC_) ? s[j*NC_ + c] : 0.f;
        dst[idx] = (_Float16)v;
    }
}

// ------- rel (MFMA): relh[n][d] = (1/(s[n]+1.6e-4)) * sum_l vh[n][l] seqT[b][d][l] -------
__global__ __launch_bounds__(256) void k_rel_mfma(const _Float16* __restrict__ vh,
                                                  const _Float16* __restrict__ seqT,
                                                  const float* __restrict__ s,
                                                  _Float16* __restrict__ relh) {
    const int d0 = blockIdx.x * 64;   // 16
    const int n0 = blockIdx.y * 64;   // 32
    const int b  = n0 >> 9;
    __shared__ _Float16 bs[2][64*64];
    const int t = threadIdx.x;
    const int w = t >> 6, lane = t & 63;
    const int r = lane & 15, g = lane >> 4;
    const int row8 = lane >> 3, u8 = lane & 7;
    const int swz_w = (u8 ^ row8) * 8;

    const _Float16* bsrc = seqT + ((size_t)(b*H_) + d0) * L_;
    #pragma unroll
    for (int c2 = w*2; c2 < w*2+2; ++c2)
        gload_lds16(bsrc + (size_t)(c2*8 + row8)*L_ + swz_w, &bs[0][c2*512]);

    const _Float16* ap = vh + (size_t)(n0 + w*16 + r) * L_;
    half8 nA0 = *(const half8*)(ap + g*8);
    half8 nA1 = *(const half8*)(ap + 32 + g*8);

    f32x4 acc[4] = {};
    __syncthreads();

    for (int c = 0; c < 16; ++c) {
        const int cur = c & 1;
        if (c < 15) {
            const int k0n = (c+1)*64;
            #pragma unroll
            for (int c2 = w*2; c2 < w*2+2; ++c2)
                gload_lds16(bsrc + (size_t)(c2*8 + row8)*L_ + k0n + swz_w, &bs[cur^1][c2*512]);
        }
        half8 cA0 = nA0, cA1 = nA1;
        if (c < 15) {
            const int k0n = (c+1)*64;
            nA0 = *(const half8*)(ap + k0n + g*8);
            nA1 = *(const half8*)(ap + k0n + 32 + g*8);
        }
        #pragma unroll
        for (int df = 0; df < 4; ++df) {
            half8 b0 = *(const half8*)&bs[cur][(df*16 + r)*64 + ((g ^ (r&7))*8)];
            acc[df] = __builtin_amdgcn_mfma_f32_16x16x32_f16(cA0, b0, acc[df], 0, 0, 0);
            half8 b1 = *(const half8*)&bs[cur][(df*16 + r)*64 + (((4+g) ^ (r&7))*8)];
            acc[df] = __builtin_amdgcn_mfma_f32_16x16x32_f16(cA1, b1, acc[df], 0, 0, 0);
        }
        __syncthreads();
    }
    const int nb = n0 + w*16 + g*4;
    float invs[4];
    #pragma unroll
    for (int q = 0; q < 4; ++q) invs[q] = 1.f / (s[nb + q] + 1.6e-4f);
    #pragma unroll
    for (int df = 0; df < 4; ++df)
        #pragma unroll
        for (int q = 0; q < 4; ++q)
            relh[(size_t)(nb + q)*H_ + d0 + df*16 + r] = (_Float16)(acc[df][q] * invs[q]);
}

// ------- extractor (MFMA): outh = half( tanh([gather(ent fp32)|relh] @ W + b) ) -------
__global__ __launch_bounds__(256) void k_extract_mfma(const float* __restrict__ ent_embeds,
                                                      const _Float16* __restrict__ relh,
                                                      const int* __restrict__ hts,
                                                      const _Float16* __restrict__ WhT,
                                                      const _Float16* __restrict__ WtT,
                                                      const float* __restrict__ bh,
                                                      const float* __restrict__ bt,
                                                      _Float16* __restrict__ hsf,
                                                      _Float16* __restrict__ tsf) {
    const int which = blockIdx.z;
    const _Float16* WT = which ? WtT : WhT;
    const float* bias  = which ? bt : bh;
    _Float16* outh     = which ? tsf : hsf;

    const int d0 = blockIdx.x * 64;      // 12
    const int n0 = blockIdx.y * 64;      // 32
    __shared__ _Float16 wt_s[2][64*64];
    const int t = threadIdx.x;
    const int w = t >> 6, lane = t & 63;
    const int r = lane & 15, g = lane >> 4;
    const int row8 = lane >> 3, u8 = lane & 7;
    const int swz_w = (u8 ^ row8) * 8;

    const int nrow = n0 + w*16 + r;
    const int hidx = hts[nrow*2 + which];
    const float* entp = ent_embeds + ((size_t)((nrow >> 9)*E_ + hidx))*H_;
    const _Float16* relp = relh + (size_t)nrow * H_;

    #pragma unroll
    for (int c2 = w*2; c2 < w*2+2; ++c2)
        gload_lds16(WT + (size_t)(d0 + c2*8 + row8)*2048 + swz_w, &wt_s[0][c2*512]);

    float4 nF0 = *(const float4*)(entp + g*8);
    float4 nF1 = *(const float4*)(entp + g*8 + 4);
    float4 nF2 = *(const float4*)(entp + 32 + g*8);
    float4 nF3 = *(const float4*)(entp + 32 + g*8 + 4);
    half8 nH0 = {}, nH1 = {};

    f32x4 acc[4] = {};
    __syncthreads();

    for (int c = 0; c < 32; ++c) {
        const int cur = c & 1;
        if (c < 31) {
            const int k0n = (c+1)*64;
            #pragma unroll
            for (int c2 = w*2; c2 < w*2+2; ++c2)
                gload_lds16(WT + (size_t)(d0 + c2*8 + row8)*2048 + k0n + swz_w,
                            &wt_s[cur^1][c2*512]);
        }
        half8 aF0, aF1;
        if (c < 16) {
            aF0 = half8{ (_Float16)nF0.x, (_Float16)nF0.y, (_Float16)nF0.z, (_Float16)nF0.w,
                         (_Float16)nF1.x, (_Float16)nF1.y, (_Float16)nF1.z, (_Float16)nF1.w };
            aF1 = half8{ (_Float16)nF2.x, (_Float16)nF2.y, (_Float16)nF2.z, (_Float16)nF2.w,
                         (_Float16)nF3.x, (_Float16)nF3.y, (_Float16)nF3.z, (_Float16)nF3.w };
        } else {
            aF0 = nH0; aF1 = nH1;
        }
        if (c < 31) {
            const int k0n = (c+1)*64;
            if (k0n < 1024) {
                const float* ar = entp + k0n;
                nF0 = *(const float4*)(ar + g*8);
                nF1 = *(const float4*)(ar + g*8 + 4);
                nF2 = *(const float4*)(ar + 32 + g*8);
                nF3 = *(const float4*)(ar + 32 + g*8 + 4);
            } else {
                const _Float16* ar = relp + (k0n - 1024);
                nH0 = *(const half8*)(ar + g*8);
                nH1 = *(const half8*)(ar + 32 + g*8);
            }
        }
        #pragma unroll
        for (int df = 0; df < 4; ++df) {
            half8 b0 = *(const half8*)&wt_s[cur][(df*16 + r)*64 + ((g ^ (r&7))*8)];
            acc[df] = __builtin_amdgcn_mfma_f32_16x16x32_f16(aF0, b0, acc[df], 0, 0, 0);
            half8 b1 = *(const half8*)&wt_s[cur][(df*16 + r)*64 + (((4+g) ^ (r&7))*8)];
            acc[df] = __builtin_amdgcn_mfma_f32_16x16x32_f16(aF1, b1, acc[df], 0, 0, 0);
        }
        __syncthreads();
    }
    #pragma unroll
    for (int df = 0; df < 4; ++df) {
        float bv = bias[d0 + df*16 + r];
        #pragma unroll
        for (int q2 = 0; q2 < 4; ++q2) {
            float v = tanhf(acc[df][q2] + bv);
            outh[(size_t)(n0 + w*16 + g*4 + q2)*EMB_ + d0 + df*16 + r] = (_Float16)v;
        }
    }
}

// ------- classifier (MFMA v2): partial[kb][n][c] = sum_{i,j} hs[n,kb*64+i] ts[n,kb*64+j] Wbt[kb*64+i][c][j]
// waves split by CLASS (wave w: classes 32w..32w+31); n-tile 128; B read global->reg (L2);
// no LDS staging / no barriers in the K-loop; fp32 partial stores (no atomics).
__global__ __launch_bounds__(256) void k_cls_mfma(const _Float16* __restrict__ hsf,
                                                  const _Float16* __restrict__ tsf,
                                                  const _Float16* __restrict__ Wbt,
                                                  float* __restrict__ partial) {
    const int kb = blockIdx.x;           // 0..11
    const int n0 = blockIdx.y * 128;     // 16 n-tiles
    const int t = threadIdx.x;
    const int w = t >> 6, lane = t & 63;
    const int r = lane & 15, g = lane >> 4;
    __shared__ _Float16 hs_s[128*72];    // [n][i 64], pad 72 (16B-aligned rows)

    {   // stage hs rows n0..n0+127, cols kb*64..+63
        int n = t & 127, hh = t >> 7;    // 2 threads/row, 32 cols each
        const _Float16* src = &hsf[(size_t)(n0+n)*EMB_ + kb*64 + hh*32];
        #pragma unroll
        for (int u = 0; u < 4; ++u)
            *(half8*)&hs_s[n*72 + hh*32 + u*8] = *(const half8*)(src + u*8);
    }
    // ts fragments: i-invariant, 8 nf x 2 jh, lane holds ts[n0+nf*16+r][kb*64+jh*32+g*8 ..+7]
    half8 tsF[8][2];
    #pragma unroll
    for (int nf = 0; nf < 8; ++nf) {
        const _Float16* tp = &tsf[(size_t)(n0 + nf*16 + r)*EMB_ + kb*64];
        tsF[nf][0] = *(const half8*)(tp + g*8);
        tsF[nf][1] = *(const half8*)(tp + 32 + g*8);
    }
    __syncthreads();

    const _Float16* wb = Wbt + (size_t)(kb*64) * 8192;   // slice (kb*64+i) stride 8192 halfs
    f32x4 acc[8][2] = {};

    #pragma unroll 2
    for (int i = 0; i < 64; ++i) {
        const _Float16* ws_ = wb + (size_t)i * 8192;
        // B fragments: lane (r,g), class row c = w*32 + cl*16 + r, j-chunk jh*32 + g*8
        half8 b00, b01, b10, b11;
        {
            const _Float16* bp0 = ws_ + (size_t)(w*32 + r)*64;
            const _Float16* bp1 = ws_ + (size_t)(w*32 + 16 + r)*64;
            b00 = *(const half8*)(bp0 + g*8);
            b01 = *(const half8*)(bp0 + 32 + g*8);
            b10 = *(const half8*)(bp1 + g*8);
            b11 = *(const half8*)(bp1 + 32 + g*8);
        }
        #pragma unroll
        for (int nf = 0; nf < 8; ++nf) {
            _Float16 h = hs_s[(nf*16 + r)*72 + i];
            half8 a0, a1;
            #pragma unroll
            for (int e = 0; e < 8; ++e) { a0[e] = tsF[nf][0][e] * h; a1[e] = tsF[nf][1][e] * h; }
            acc[nf][0] = __builtin_amdgcn_mfma_f32_16x16x32_f16(a0, b00, acc[nf][0], 0, 0, 0);
            acc[nf][0] = __builtin_amdgcn_mfma_f32_16x16x32_f16(a1, b01, acc[nf][0], 0, 0, 0);
            acc[nf][1] = __builtin_amdgcn_mfma_f32_16x16x32_f16(a0, b10, acc[nf][1], 0, 0, 0);
            acc[nf][1] = __builtin_amdgcn_mfma_f32_16x16x32_f16(a1, b11, acc[nf][1], 0, 0, 0);
        }
    }
    // D: col = r -> class c = w*32 + cl*16 + r ; row = g*4+q -> n = n0 + nf*16 + g*4 + q
    float* pdst = partial + (size_t)kb * 2048 * 128;
    #pragma unroll
    for (int nf = 0; nf < 8; ++nf) {
        #pragma unroll
        for (int cl = 0; cl < 2; ++cl) {
            int c = w*32 + cl*16 + r;
            #pragma unroll
            for (int q = 0; q < 4; ++q)
                pdst[(size_t)(n0 + nf*16 + g*4 + q)*128 + c] = acc[nf][cl][q];
        }
    }
}

// ---------------- reduce partials + bias -> logits ----------------
__global__ __launch_bounds__(256) void k_reduce(const float* __restrict__ partial,
                                                const float* __restrict__ bb,
                                                float* __restrict__ out) {
    int idx = blockIdx.x*256 + threadIdx.x;
    if (idx >= NPAIR_*NC_) return;
    int n = idx / NC_, c = idx - n*NC_;
    float s = bb[c];
    #pragma unroll
    for (int kb = 0; kb < 12; ++kb)
        s += partial[((size_t)kb*2048 + n)*128 + c];
    out[idx] = s;
}

extern "C" void kernel_launch(void* const* d_in, const int* in_sizes, int n_in,
                              void* d_out, int out_size, void* d_ws, size_t ws_size,
                              hipStream_t stream) {
    (void)in_sizes; (void)n_in; (void)out_size; (void)ws_size;
    const float* seq  = (const float*)d_in[0];
    const float* ent  = (const float*)d_in[1];
    const float* attn = (const float*)d_in[2];
    const int*   lbl  = (const int*)d_in[3];
    const int*   hts  = (const int*)d_in[4];
    const float* Wh   = (const float*)d_in[5];
    const float* bh   = (const float*)d_in[6];
    const float* Wt   = (const float*)d_in[7];
    const float* bt   = (const float*)d_in[8];
    const float* Wb   = (const float*)d_in[9];
    const float* bb   = (const float*)d_in[10];
    float* out = (float*)d_out;
    float* ws  = (float*)d_ws;

    float*    ent_embeds = ws + OFF_ENT;
    _Float16* ea_t = (_Float16*)(ws + OFF_ATTNH);
    _Float16* vh   = (_Float16*)(ws + OFF_VH);
    float*    sv   = ws + OFF_S;
    _Float16* seqT = (_Float16*)(ws + OFF_SEQT);
    _Float16* relh = (_Float16*)(ws + OFF_RELH);
    _Float16* hsf  = (_Float16*)(ws + OFF_HSF);
    _Float16* tsf  = (_Float16*)(ws + OFF_TSF);
    _Float16* WhT  = (_Float16*)(ws + OFF_WHT);
    _Float16* WtT  = (_Float16*)(ws + OFF_WTT);
    _Float16* Wbt  = (_Float16*)(ws + OFF_ATTNH);  // aliases ea_t+vh; written after k_rel
    float*    part = ws + OFF_SEQT;                // aliases seqT+relh; written after extract

    k_prep_seqt<<<dim3(16, 16, 4), 256, 0, stream>>>(seq, seqT);
    k_prep_wt<<<dim3(32, 12), 256, 0, stream>>>(Wh, WhT);
    k_prep_wt<<<dim3(32, 12), 256, 0, stream>>>(Wt, WtT);
    k_ent_pool<<<B_*E_, 256, 0, stream>>>(ent, lbl, ent_embeds);
    k_ent_attn<<<B_*E_, 256, 0, stream>>>(attn, lbl, ea_t);
    k_ht<<<B_*64, 256, 0, stream>>>(ea_t, hts, vh);
    k_rowsum<<<NPAIR_/4, 256, 0, stream>>>(vh, sv);
    k_rel_mfma<<<dim3(16, 32), 256, 0, stream>>>(vh, seqT, sv, relh);
    k_prep_wbt<<<768, 256, 0, stream>>>(Wb, Wbt);   // after k_ht + k_rel: alias region dead
    k_extract_mfma<<<dim3(12, 32, 2), 256, 0, stream>>>(ent_embeds, relh, hts, WhT, WtT, bh, bt, hsf, tsf);
    k_cls_mfma<<<dim3(12, 16), 256, 0, stream>>>(hsf, tsf, Wbt, part);  // after extract: relh dead
    k_reduce<<<(NPAIR_*NC_ + 255)/256, 256, 0, stream>>>(part, bb, out);
}

// Round 6
// 281.179 us; speedup vs baseline: 3.8116x; 1.0405x over previous
//
#include <hip/hip_runtime.h>
#include <cmath>

#define B_ 4
#define M_ 128
#define H_ 1024
#define NH_ 16
#define L_ 1024
#define E_ 64
#define R_ 512
#define EMB_ 768
#define BS_ 64
#define NC_ 97
#define NPAIR_ (B_*R_)   // 2048
#define LC_ 16           // l-chunk in k_ht

typedef _Float16 half8 __attribute__((ext_vector_type(8)));
typedef float f32x4 __attribute__((ext_vector_type(4)));

// ---------------- workspace layout (float offsets), total 11,143,168 fl = 44.6 MB ----------------
// S1 [0, 3145728): ea_t half (2097152 fl) + vh half (1048576 fl); later part fp32 [12][2048][128]
#define OFF_EAT    0
#define OFF_VH     2097152
#define OFF_PART   0
// S2 [3145728, 5242880): seqT half [4][1024][1024]; later G half [2304][1536] (1769472 fl)
#define OFF_SEQT   3145728
#define OFF_G      3145728
// S3 [5242880, 6291456): relh half [2048][1024]
#define OFF_RELH   5242880
#define OFF_WBT    6291456   // Wbt half [768][128][64] (3145728 fl)
#define OFF_ENTH   9437184   // enth half [256][1024] (131072 fl)
#define OFF_SV     9568256   // fp32 [2048]
#define OFF_WHT    9570304   // WhT half [768][2048] (786432 fl); hsf aliases after k_bigmm
#define OFF_WTT    10356736  // WtT half [768][2048] (786432 fl); tsf aliases after k_bigmm

__device__ __forceinline__ void gload_lds16(const void* g, void* l) {
    __builtin_amdgcn_global_load_lds(
        (const __attribute__((address_space(1))) unsigned int*)g,
        (__attribute__((address_space(3))) unsigned int*)l, 16, 0, 0);
}

// ---------------- mention -> entity logsumexp pooling (half output) ----------------
__global__ __launch_bounds__(256) void k_ent_pool(const float* __restrict__ ent_lhs,
                                                  const int* __restrict__ labels,
                                                  _Float16* __restrict__ enth) {
    int blk = blockIdx.x;
    int b = blk >> 6, e = blk & 63;
    __shared__ int lbl[M_];
    int t = threadIdx.x;
    if (t < M_) lbl[t] = labels[b*M_ + t];
    __syncthreads();
    const float* src = ent_lhs + (size_t)b * M_ * H_;
    float mx[4], sm[4];
    #pragma unroll
    for (int j = 0; j < 4; ++j) { mx[j] = -INFINITY; sm[j] = 0.f; }
    int cnt = 0;
    for (int m = 0; m < M_; ++m) {
        if (lbl[m] != e) continue;
        ++cnt;
        const float* row = src + m * H_;
        #pragma unroll
        for (int j = 0; j < 4; ++j) {
            float x = row[t + j*256];
            if (x > mx[j]) { sm[j] = sm[j] * __expf(mx[j] - x) + 1.f; mx[j] = x; }
            else           { sm[j] += __expf(x - mx[j]); }
        }
    }
    _Float16* dst = enth + (size_t)blk * H_;
    #pragma unroll
    for (int j = 0; j < 4; ++j)
        dst[t + j*256] = (_Float16)((cnt > 0) ? (mx[j] + __logf(sm[j])) : 0.f);
}

// ------- mention -> entity mean attention, TRANSPOSED half output [b][e][l][nh] -------
__global__ __launch_bounds__(256) void k_ent_attn(const float* __restrict__ attn,
                                                  const int* __restrict__ labels,
                                                  _Float16* __restrict__ ea_t) {
    int blk = blockIdx.x;            // b*64 + e
    int b = blk >> 6, e = blk & 63;
    __shared__ int lbl[M_];
    int t = threadIdx.x;
    if (t < M_) lbl[t] = labels[b*M_ + t];
    __syncthreads();
    const float* src = attn + (size_t)b * NH_ * M_ * L_;
    float acc[16][4] = {};
    int cnt = 0;
    for (int m = 0; m < M_; ++m) {
        if (lbl[m] != e) continue;
        ++cnt;
        const float* mp = src + (size_t)m * L_ + t*4;
        #pragma unroll
        for (int nh = 0; nh < 16; ++nh) {
            float4 v = *(const float4*)(mp + (size_t)nh * M_ * L_);
            acc[nh][0] += v.x; acc[nh][1] += v.y; acc[nh][2] += v.z; acc[nh][3] += v.w;
        }
    }
    float inv = 1.f / fmaxf((float)cnt, 1.f);
    _Float16* dst = ea_t + (size_t)blk * L_ * 16;
    #pragma unroll
    for (int j = 0; j < 4; ++j) {
        int l = t*4 + j;
        half8 o0, o1;
        #pragma unroll
        for (int nh = 0; nh < 8; ++nh) { o0[nh] = (_Float16)(acc[nh][j]*inv); o1[nh] = (_Float16)(acc[nh+8][j]*inv); }
        *(half8*)(dst + (size_t)l*16)     = o0;
        *(half8*)(dst + (size_t)l*16 + 8) = o1;
    }
}

// ------- per-pair attn product, LDS-tiled: vh[n][l] = sum_nh ha*ta (unnormalized) -------
__global__ __launch_bounds__(256) void k_ht(const _Float16* __restrict__ ea_t,
                                            const int* __restrict__ hts,
                                            _Float16* __restrict__ vh) {
    int blk = blockIdx.x;            // b*64 + lc
    int b = blk >> 6, lc = blk & 63;
    int l0 = lc * LC_;
    __shared__ _Float16 tile[64*256];
    int t = threadIdx.x;
    {
        int e = t >> 2, part = t & 3;
        const _Float16* src = ea_t + ((size_t)(b*64 + e)*L_ + l0) * 16;
        #pragma unroll
        for (int u = 0; u < 8; ++u) {
            int unit = part*8 + u;
            int l = unit >> 1, nhh = unit & 1;
            half8 v = *(const half8*)(src + l*16 + nhh*8);
            *(half8*)&tile[e*256 + ((l ^ (e & 15))*16) + nhh*8] = v;
        }
    }
    __syncthreads();
    const int* hp = hts + b * R_ * 2;
    #pragma unroll
    for (int pp = 0; pp < 2; ++pp) {
        int p = pp*256 + t;
        int he = hp[p*2], te = hp[p*2 + 1];
        const _Float16* ha = &tile[he*256];
        const _Float16* ta = &tile[te*256];
        float accl[LC_];
        #pragma unroll
        for (int l = 0; l < LC_; ++l) {
            half8 h0 = *(const half8*)&ha[((l ^ (he & 15))*16)];
            half8 h1 = *(const half8*)&ha[((l ^ (he & 15))*16) + 8];
            half8 t0 = *(const half8*)&ta[((l ^ (te & 15))*16)];
            half8 t1 = *(const half8*)&ta[((l ^ (te & 15))*16) + 8];
            float s = 0.f;
            #pragma unroll
            for (int q = 0; q < 8; ++q)
                s += (float)h0[q]*(float)t0[q] + (float)h1[q]*(float)t1[q];
            accl[l] = s;
        }
        half8 o0, o1;
        #pragma unroll
        for (int q = 0; q < 8; ++q) { o0[q] = (_Float16)accl[q]; o1[q] = (_Float16)accl[q+8]; }
        _Float16* dst = vh + (size_t)(b*R_ + p)*L_ + l0;
        *(half8*)dst = o0;
        *(half8*)(dst + 8) = o1;
    }
}

// ---------------- row sums s[n] = sum_l vh[n][l] ----------------
__global__ __launch_bounds__(256) void k_rowsum(const _Float16* __restrict__ vh,
                                                float* __restrict__ s) {
    int row = blockIdx.x*4 + (threadIdx.x >> 6);
    int lane = threadIdx.x & 63;
    const _Float16* r = vh + (size_t)row * L_;
    float acc = 0.f;
    #pragma unroll
    for (int u = 0; u < 2; ++u) {
        half8 v = *(const half8*)(r + (lane + u*64)*8);
        #pragma unroll
        for (int q = 0; q < 8; ++q) acc += (float)v[q];
    }
    #pragma unroll
    for (int off = 32; off > 0; off >>= 1) acc += __shfl_down(acc, off);
    if (lane == 0) s[row] = acc;
}

// ---------------- prep: seq [b][l][d] fp32 -> seqT [b][d][l] half ----------------
__global__ __launch_bounds__(256) void k_prep_seqt(const float* __restrict__ seq,
                                                   _Float16* __restrict__ seqT) {
    int l0 = blockIdx.x*64, d0 = blockIdx.y*64, b = blockIdx.z;
    __shared__ _Float16 sl[64*72];
    int t = threadIdx.x;
    int lr = t >> 4, dc = (t & 15)*4;
    #pragma unroll
    for (int u = 0; u < 4; ++u) {
        int l = lr + u*16;
        float4 v = *(const float4*)(seq + ((size_t)(b*L_ + l0 + l))*H_ + d0 + dc);
        sl[l*72 + dc+0] = (_Float16)v.x; sl[l*72 + dc+1] = (_Float16)v.y;
        sl[l*72 + dc+2] = (_Float16)v.z; sl[l*72 + dc+3] = (_Float16)v.w;
    }
    __syncthreads();
    int d = t >> 2, lo = (t & 3)*16;
    half8 o0, o1;
    #pragma unroll
    for (int q = 0; q < 8; ++q) { o0[q] = sl[(lo+q)*72 + d]; o1[q] = sl[(lo+8+q)*72 + d]; }
    _Float16* dst = seqT + ((size_t)(b*H_ + d0 + d))*L_ + l0 + lo;
    *(half8*)dst = o0;
    *(half8*)(dst + 8) = o1;
}

// ---------------- prep: W[2048][768] fp32 -> WT[768][2048] half ----------------
__global__ __launch_bounds__(256) void k_prep_wt(const float* __restrict__ W,
                                                 _Float16* __restrict__ WT) {
    int k0 = blockIdx.x * 64;
    int d0 = blockIdx.y * 64;
    __shared__ float s[64*65];
    int t = threadIdx.x;
    #pragma unroll
    for (int u = 0; u < 16; ++u) {
        int idx = t + u*256; int rr = idx >> 6, cc = idx & 63;
        s[rr*65 + cc] = W[(size_t)(k0+rr)*EMB_ + d0 + cc];
    }
    __syncthreads();
    #pragma unroll
    for (int u = 0; u < 16; ++u) {
        int idx = t + u*256; int dd = idx >> 6, kk = idx & 63;
        WT[(size_t)(d0+dd)*2048 + k0 + kk] = (_Float16)s[kk*65 + dd];
    }
}

// --------- prep: Wb[49152][97] fp32 -> Wbt[768 slices][128 c][64 j] half ---------
__global__ __launch_bounds__(256) void k_prep_wbt(const float* __restrict__ Wb,
                                                  _Float16* __restrict__ Wbt) {
    int kbi = blockIdx.x;
    __shared__ float s[64*97];
    int t = threadIdx.x;
    size_t gbase = (size_t)kbi * 64 * NC_;
    #pragma unroll
    for (int u = 0; u < 25; ++u) {
        int idx = t + u*256;
        if (idx < 64*NC_) s[idx] = Wb[gbase + idx];
    }
    __syncthreads();
    _Float16* dst = Wbt + (size_t)kbi * 8192;
    #pragma unroll
    for (int u = 0; u < 32; ++u) {
        int idx = t + u*256;
        int c = idx >> 6, j = idx & 63;
        float v = (c < NC_) ? s[j*NC_ + c] : 0.f;
        dst[idx] = (_Float16)v;
    }
}

// ------- rel (MFMA 128x64 tiles): relh[n][d] = invs[n] * sum_l vh[n][l] seqT[b][d][l] -------
__global__ __launch_bounds__(256) void k_relmm(const _Float16* __restrict__ vh,
                                               const _Float16* __restrict__ seqT,
                                               const float* __restrict__ sv,
                                               _Float16* __restrict__ relh) {
    const int nt = blockIdx.x;        // 0..15 (d-tile 64)
    const int mt = blockIdx.y;        // 0..15 (pair-tile 128)
    const int b  = mt >> 2;
    __shared__ _Float16 As[2][128*64];
    __shared__ _Float16 Bs[2][64*64];
    const int t = threadIdx.x;
    const int w = t >> 6, lane = t & 63;
    const int r = lane & 15, g = lane >> 4;
    const int wm = w >> 1, wn = w & 1;
    const int srow = lane >> 3, scol = ((lane & 7) ^ srow) * 8;

    const _Float16* Ab = vh + (size_t)mt*128*1024;
    const _Float16* Bb = seqT + ((size_t)b*1024 + nt*64)*1024;

    #pragma unroll
    for (int cc = 0; cc < 6; ++cc) {
        int c = w*6 + cc;
        if (c < 16) gload_lds16(Ab + (size_t)(c*8 + srow)*1024 + scol, &As[0][c*512]);
        else        gload_lds16(Bb + (size_t)((c-16)*8 + srow)*1024 + scol, &Bs[0][(c-16)*512]);
    }
    f32x4 acc[4][2] = {};
    __syncthreads();

    for (int k = 0; k < 16; ++k) {
        const int cur = k & 1;
        if (k < 15) {
            const int k0 = (k+1)*64;
            #pragma unroll
            for (int cc = 0; cc < 6; ++cc) {
                int c = w*6 + cc;
                if (c < 16) gload_lds16(Ab + (size_t)(c*8 + srow)*1024 + k0 + scol, &As[cur^1][c*512]);
                else        gload_lds16(Bb + (size_t)((c-16)*8 + srow)*1024 + k0 + scol, &Bs[cur^1][(c-16)*512]);
            }
        }
        half8 aF[4][2], bF[2][2];
        #pragma unroll
        for (int mf = 0; mf < 4; ++mf) {
            int row = wm*64 + mf*16 + r;
            aF[mf][0] = *(const half8*)&As[cur][row*64 + ((g ^ (r&7))*8)];
            aF[mf][1] = *(const half8*)&As[cur][row*64 + (((4+g) ^ (r&7))*8)];
        }
        #pragma unroll
        for (int nf = 0; nf < 2; ++nf) {
            int row = wn*32 + nf*16 + r;
            bF[nf][0] = *(const half8*)&Bs[cur][row*64 + ((g ^ (r&7))*8)];
            bF[nf][1] = *(const half8*)&Bs[cur][row*64 + (((4+g) ^ (r&7))*8)];
        }
        #pragma unroll
        for (int mf = 0; mf < 4; ++mf)
            #pragma unroll
            for (int nf = 0; nf < 2; ++nf) {
                acc[mf][nf] = __builtin_amdgcn_mfma_f32_16x16x32_f16(aF[mf][0], bF[nf][0], acc[mf][nf], 0, 0, 0);
                acc[mf][nf] = __builtin_amdgcn_mfma_f32_16x16x32_f16(aF[mf][1], bF[nf][1], acc[mf][nf], 0, 0, 0);
            }
        __syncthreads();
    }
    #pragma unroll
    for (int mf = 0; mf < 4; ++mf) {
        int nb = mt*128 + wm*64 + mf*16 + g*4;
        float invs[4];
        #pragma unroll
        for (int q = 0; q < 4; ++q) invs[q] = 1.f / (sv[nb + q] + 1.6e-4f);
        #pragma unroll
        for (int nf = 0; nf < 2; ++nf) {
            int d = nt*64 + wn*32 + nf*16 + r;
            #pragma unroll
            for (int q = 0; q < 4; ++q)
                relh[(size_t)(nb + q)*1024 + d] = (_Float16)(acc[mf][nf][q] * invs[q]);
        }
    }
}

// ------- big GEMM (128x128 tiles): G = [relh;enth] @ [W2|W1 halves of Wh,Wt] -------
// A rows 0..2047 = relh (uses W k-offset 1024: rel half); rows 2048..2303 = enth
// (uses W k-offset 0: ent half).
__global__ __launch_bounds__(256) void k_bigmm(const _Float16* __restrict__ relh,
                                               const _Float16* __restrict__ enth,
                                               const _Float16* __restrict__ WhT,
                                               const _Float16* __restrict__ WtT,
                                               _Float16* __restrict__ G) {
    const int nt = blockIdx.x;        // 0..11 (col tile 128 of 1536)
    const int mt = blockIdx.y;        // 0..17 (row tile 128 of 2304)
    __shared__ _Float16 As[2][128*64];
    __shared__ _Float16 Bs[2][128*64];
    const int t = threadIdx.x;
    const int w = t >> 6, lane = t & 63;
    const int r = lane & 15, g = lane >> 4;
    const int wm = w >> 1, wn = w & 1;
    const int srow = lane >> 3, scol = ((lane & 7) ^ srow) * 8;

    const _Float16* Ab = (mt < 16) ? (relh + (size_t)mt*128*1024)
                                   : (enth + (size_t)(mt-16)*128*1024);
    const int koff = (mt < 16) ? 1024 : 0;     // rel rows use W[1024:2048], ent rows W[0:1024]
    const _Float16* Bb = ((nt < 6) ? (WhT + (size_t)nt*128*2048)
                                   : (WtT + (size_t)(nt-6)*128*2048)) + koff;

    #pragma unroll
    for (int cc = 0; cc < 4; ++cc) {
        int c = w*4 + cc;
        gload_lds16(Ab + (size_t)(c*8 + srow)*1024 + scol, &As[0][c*512]);
        gload_lds16(Bb + (size_t)(c*8 + srow)*2048 + scol, &Bs[0][c*512]);
    }
    f32x4 acc[4][4] = {};
    __syncthreads();

    for (int k = 0; k < 16; ++k) {
        const int cur = k & 1;
        if (k < 15) {
            const int k0 = (k+1)*64;
            #pragma unroll
            for (int cc = 0; cc < 4; ++cc) {
                int c = w*4 + cc;
                gload_lds16(Ab + (size_t)(c*8 + srow)*1024 + k0 + scol, &As[cur^1][c*512]);
                gload_lds16(Bb + (size_t)(c*8 + srow)*2048 + k0 + scol, &Bs[cur^1][c*512]);
            }
        }
        half8 aF[4][2], bF[4][2];
        #pragma unroll
        for (int mf = 0; mf < 4; ++mf) {
            int row = wm*64 + mf*16 + r;
            aF[mf][0] = *(const half8*)&As[cur][row*64 + ((g ^ (r&7))*8)];
            aF[mf][1] = *(const half8*)&As[cur][row*64 + (((4+g) ^ (r&7))*8)];
        }
        #pragma unroll
        for (int nf = 0; nf < 4; ++nf) {
            int row = wn*64 + nf*16 + r;
            bF[nf][0] = *(const half8*)&Bs[cur][row*64 + ((g ^ (r&7))*8)];
            bF[nf][1] = *(const half8*)&Bs[cur][row*64 + (((4+g) ^ (r&7))*8)];
        }
        #pragma unroll
        for (int mf = 0; mf < 4; ++mf)
            #pragma unroll
            for (int nf = 0; nf < 4; ++nf) {
                acc[mf][nf] = __builtin_amdgcn_mfma_f32_16x16x32_f16(aF[mf][0], bF[nf][0], acc[mf][nf], 0, 0, 0);
                acc[mf][nf] = __builtin_amdgcn_mfma_f32_16x16x32_f16(aF[mf][1], bF[nf][1], acc[mf][nf], 0, 0, 0);
            }
        __syncthreads();
    }
    #pragma unroll
    for (int mf = 0; mf < 4; ++mf) {
        int nrow = mt*128 + wm*64 + mf*16 + g*4;
        #pragma unroll
        for (int nf = 0; nf < 4; ++nf) {
            int v = nt*128 + wn*64 + nf*16 + r;
            #pragma unroll
            for (int q = 0; q < 4; ++q)
                G[(size_t)(nrow + q)*1536 + v] = (_Float16)acc[mf][nf][q];
        }
    }
}

// ------- combine: hsf/tsf = tanh(relW + gather(entW) + bias), all from G -------
__global__ __launch_bounds__(192) void k_combine(const _Float16* __restrict__ G,
                                                 const int* __restrict__ hts,
                                                 const float* __restrict__ bh,
                                                 const float* __restrict__ bt,
                                                 _Float16* __restrict__ hsf,
                                                 _Float16* __restrict__ tsf) {
    int n = blockIdx.x;
    int b = n >> 9;
    int t = threadIdx.x;
    int side = t / 96, u = t % 96;
    int d0 = u*8;
    int idx = hts[n*2 + side];
    const _Float16* grel = G + (size_t)n*1536 + side*768 + d0;
    const _Float16* gent = G + (size_t)(2048 + b*64 + idx)*1536 + side*768 + d0;
    const float* bias = side ? bt : bh;
    half8 a = *(const half8*)grel;
    half8 e = *(const half8*)gent;
    half8 o;
    #pragma unroll
    for (int q = 0; q < 8; ++q)
        o[q] = (_Float16)tanhf((float)a[q] + (float)e[q] + bias[d0+q]);
    _Float16* dst = (side ? tsf : hsf) + (size_t)n*EMB_ + d0;
    *(half8*)dst = o;
}

// ------- classifier (MFMA): partial[kb][n][c]; waves split by class; B global->reg -------
__global__ __launch_bounds__(256) void k_cls_mfma(const _Float16* __restrict__ hsf,
                                                  const _Float16* __restrict__ tsf,
                                                  const _Float16* __restrict__ Wbt,
                                                  float* __restrict__ partial) {
    const int kb = blockIdx.x;           // 0..11
    const int n0 = blockIdx.y * 128;     // 16 n-tiles
    const int t = threadIdx.x;
    const int w = t >> 6, lane = t & 63;
    const int r = lane & 15, g = lane >> 4;
    __shared__ _Float16 hs_s[128*72];

    {
        int n = t & 127, hh = t >> 7;
        const _Float16* src = &hsf[(size_t)(n0+n)*EMB_ + kb*64 + hh*32];
        #pragma unroll
        for (int u = 0; u < 4; ++u)
            *(half8*)&hs_s[n*72 + hh*32 + u*8] = *(const half8*)(src + u*8);
    }
    half8 tsF[8][2];
    #pragma unroll
    for (int nf = 0; nf < 8; ++nf) {
        const _Float16* tp = &tsf[(size_t)(n0 + nf*16 + r)*EMB_ + kb*64];
        tsF[nf][0] = *(const half8*)(tp + g*8);
        tsF[nf][1] = *(const half8*)(tp + 32 + g*8);
    }
    __syncthreads();

    const _Float16* wb = Wbt + (size_t)(kb*64) * 8192;
    f32x4 acc[8][2] = {};

    #pragma unroll 2
    for (int i = 0; i < 64; ++i) {
        const _Float16* ws_ = wb + (size_t)i * 8192;
        half8 b00, b01, b10, b11;
        {
            const _Float16* bp0 = ws_ + (size_t)(w*32 + r)*64;
            const _Float16* bp1 = ws_ + (size_t)(w*32 + 16 + r)*64;
            b00 = *(const half8*)(bp0 + g*8);
            b01 = *(const half8*)(bp0 + 32 + g*8);
            b10 = *(const half8*)(bp1 + g*8);
            b11 = *(const half8*)(bp1 + 32 + g*8);
        }
        #pragma unroll
        for (int nf = 0; nf < 8; ++nf) {
            _Float16 h = hs_s[(nf*16 + r)*72 + i];
            half8 a0, a1;
            #pragma unroll
            for (int e = 0; e < 8; ++e) { a0[e] = tsF[nf][0][e] * h; a1[e] = tsF[nf][1][e] * h; }
            acc[nf][0] = __builtin_amdgcn_mfma_f32_16x16x32_f16(a0, b00, acc[nf][0], 0, 0, 0);
            acc[nf][0] = __builtin_amdgcn_mfma_f32_16x16x32_f16(a1, b01, acc[nf][0], 0, 0, 0);
            acc[nf][1] = __builtin_amdgcn_mfma_f32_16x16x32_f16(a0, b10, acc[nf][1], 0, 0, 0);
            acc[nf][1] = __builtin_amdgcn_mfma_f32_16x16x32_f16(a1, b11, acc[nf][1], 0, 0, 0);
        }
    }
    float* pdst = partial + (size_t)kb * 2048 * 128;
    #pragma unroll
    for (int nf = 0; nf < 8; ++nf) {
        #pragma unroll
        for (int cl = 0; cl < 2; ++cl) {
            int c = w*32 + cl*16 + r;
            #pragma unroll
            for (int q = 0; q < 4; ++q)
                pdst[(size_t)(n0 + nf*16 + g*4 + q)*128 + c] = acc[nf][cl][q];
        }
    }
}

// ---------------- reduce partials + bias -> logits ----------------
__global__ __launch_bounds__(256) void k_reduce(const float* __restrict__ partial,
                                                const float* __restrict__ bb,
                                                float* __restrict__ out) {
    int idx = blockIdx.x*256 + threadIdx.x;
    if (idx >= NPAIR_*NC_) return;
    int n = idx / NC_, c = idx - n*NC_;
    float s = bb[c];
    #pragma unroll
    for (int kb = 0; kb < 12; ++kb)
        s += partial[((size_t)kb*2048 + n)*128 + c];
    out[idx] = s;
}

extern "C" void kernel_launch(void* const* d_in, const int* in_sizes, int n_in,
                              void* d_out, int out_size, void* d_ws, size_t ws_size,
                              hipStream_t stream) {
    (void)in_sizes; (void)n_in; (void)out_size; (void)ws_size;
    const float* seq  = (const float*)d_in[0];
    const float* ent  = (const float*)d_in[1];
    const float* attn = (const float*)d_in[2];
    const int*   lbl  = (const int*)d_in[3];
    const int*   hts  = (const int*)d_in[4];
    const float* Wh   = (const float*)d_in[5];
    const float* bh   = (const float*)d_in[6];
    const float* Wt   = (const float*)d_in[7];
    const float* bt   = (const float*)d_in[8];
    const float* Wb   = (const float*)d_in[9];
    const float* bb   = (const float*)d_in[10];
    float* out = (float*)d_out;
    float* ws  = (float*)d_ws;

    _Float16* ea_t = (_Float16*)(ws + OFF_EAT);
    _Float16* vh   = (_Float16*)(ws + OFF_VH);
    float*    part = ws + OFF_PART;
    _Float16* seqT = (_Float16*)(ws + OFF_SEQT);
    _Float16* G    = (_Float16*)(ws + OFF_G);
    _Float16* relh = (_Float16*)(ws + OFF_RELH);
    _Float16* Wbt  = (_Float16*)(ws + OFF_WBT);
    _Float16* enth = (_Float16*)(ws + OFF_ENTH);
    float*    sv   = ws + OFF_SV;
    _Float16* WhT  = (_Float16*)(ws + OFF_WHT);
    _Float16* WtT  = (_Float16*)(ws + OFF_WTT);
    _Float16* hsf  = (_Float16*)(ws + OFF_WHT);   // aliases WhT (dead after k_bigmm)
    _Float16* tsf  = (_Float16*)(ws + OFF_WTT);   // aliases WtT (dead after k_bigmm)

    k_prep_seqt<<<dim3(16, 16, 4), 256, 0, stream>>>(seq, seqT);
    k_prep_wt<<<dim3(32, 12), 256, 0, stream>>>(Wh, WhT);
    k_prep_wt<<<dim3(32, 12), 256, 0, stream>>>(Wt, WtT);
    k_prep_wbt<<<768, 256, 0, stream>>>(Wb, Wbt);
    k_ent_pool<<<B_*E_, 256, 0, stream>>>(ent, lbl, enth);
    k_ent_attn<<<B_*E_, 256, 0, stream>>>(attn, lbl, ea_t);
    k_ht<<<B_*64, 256, 0, stream>>>(ea_t, hts, vh);
    k_rowsum<<<NPAIR_/4, 256, 0, stream>>>(vh, sv);
    k_relmm<<<dim3(16, 16), 256, 0, stream>>>(vh, seqT, sv, relh);
    k_bigmm<<<dim3(12, 18), 256, 0, stream>>>(relh, enth, WhT, WtT, G);   // overwrites seqT (dead)
    k_combine<<<NPAIR_, 192, 0, stream>>>(G, hts, bh, bt, hsf, tsf);      // overwrites WhT/WtT (dead)
    k_cls_mfma<<<dim3(12, 16), 256, 0, stream>>>(hsf, tsf, Wbt, part);    // overwrites ea_t+vh (dead)
    k_reduce<<<(NPAIR_*NC_ + 255)/256, 256, 0, stream>>>(part, bb, out);
}

// Round 8
// 253.788 us; speedup vs baseline: 4.2230x; 1.1079x over previous
//
#include <hip/hip_runtime.h>
#include <cmath>

#define B_ 4
#define M_ 128
#define H_ 1024
#define NH_ 16
#define L_ 1024
#define E_ 64
#define R_ 512
#define EMB_ 768
#define BS_ 64
#define NC_ 97
#define NPAIR_ (B_*R_)   // 2048
#define LC_ 16           // l-chunk in k_ht

typedef _Float16 half8 __attribute__((ext_vector_type(8)));
typedef float f32x4 __attribute__((ext_vector_type(4)));

// ---------------- workspace layout (float offsets), total 11,143,168 fl = 44.6 MB ----------------
#define OFF_EAT    0
#define OFF_VH     2097152
#define OFF_PART   0
#define OFF_SEQT   3145728
#define OFF_G      3145728
#define OFF_RELH   5242880
#define OFF_WBT    6291456   // Wbt half [768][128][64] (3145728 fl)
#define OFF_ENTH   9437184   // enth half [256][1024] (131072 fl)
#define OFF_SV     9568256   // fp32 [2048]
#define OFF_WHT    9570304   // WhT half [768][2048]; hsf aliases after k_bigmm
#define OFF_WTT    10356736  // WtT half [768][2048]; tsf aliases after k_bigmm

__device__ __forceinline__ void gload_lds16(const void* g, void* l) {
    __builtin_amdgcn_global_load_lds(
        (const __attribute__((address_space(1))) unsigned int*)g,
        (__attribute__((address_space(3))) unsigned int*)l, 16, 0, 0);
}

// ------------- fused prep: seqT | WhT | WtT | Wbt | ent_pool | ent_attn | zero sv -------------
// flat grid (3080 blocks): [0,1024) seqt, [1024,1408) Wh, [1408,1792) Wt,
// [1792,2560) wbt, [2560,2816) pool, [2816,3072) attn, [3072,3080) zero-sv
__global__ __launch_bounds__(256) void k_prep_fused(const float* __restrict__ seq,
                                                    const float* __restrict__ Wh,
                                                    const float* __restrict__ Wt,
                                                    const float* __restrict__ Wb,
                                                    const float* __restrict__ ent_lhs,
                                                    const float* __restrict__ attn,
                                                    const int* __restrict__ labels,
                                                    _Float16* __restrict__ seqT,
                                                    _Float16* __restrict__ WhT,
                                                    _Float16* __restrict__ WtT,
                                                    _Float16* __restrict__ Wbt,
                                                    _Float16* __restrict__ enth,
                                                    _Float16* __restrict__ ea_t,
                                                    float* __restrict__ sv) {
    __shared__ __align__(16) char smem_raw[24832];
    const int bid = blockIdx.x;
    const int t = threadIdx.x;

    if (bid < 1024) {
        // ---- seq [b][l][d] fp32 -> seqT [b][d][l] half ----
        _Float16* sl = (_Float16*)smem_raw;            // [64][72]
        int l0 = (bid & 15)*64, d0 = ((bid >> 4) & 15)*64, b = bid >> 8;
        int lr = t >> 4, dc = (t & 15)*4;
        #pragma unroll
        for (int u = 0; u < 4; ++u) {
            int l = lr + u*16;
            float4 v = *(const float4*)(seq + ((size_t)(b*L_ + l0 + l))*H_ + d0 + dc);
            sl[l*72 + dc+0] = (_Float16)v.x; sl[l*72 + dc+1] = (_Float16)v.y;
            sl[l*72 + dc+2] = (_Float16)v.z; sl[l*72 + dc+3] = (_Float16)v.w;
        }
        __syncthreads();
        int d = t >> 2, lo = (t & 3)*16;
        half8 o0, o1;
        #pragma unroll
        for (int q = 0; q < 8; ++q) { o0[q] = sl[(lo+q)*72 + d]; o1[q] = sl[(lo+8+q)*72 + d]; }
        _Float16* dst = seqT + ((size_t)(b*H_ + d0 + d))*L_ + l0 + lo;
        *(half8*)dst = o0;
        *(half8*)(dst + 8) = o1;
    } else if (bid < 1792) {
        // ---- W[2048][768] fp32 -> WT[768][2048] half ----
        const bool isH = bid < 1408;
        const float* W = isH ? Wh : Wt;
        _Float16* WT = isH ? WhT : WtT;
        int i = bid - (isH ? 1024 : 1408);
        int k0 = (i & 31)*64, d0 = (i >> 5)*64;
        float* s = (float*)smem_raw;                   // [64][65]
        #pragma unroll
        for (int u = 0; u < 16; ++u) {
            int idx = t + u*256; int rr = idx >> 6, cc = idx & 63;
            s[rr*65 + cc] = W[(size_t)(k0+rr)*EMB_ + d0 + cc];
        }
        __syncthreads();
        #pragma unroll
        for (int u = 0; u < 16; ++u) {
            int idx = t + u*256; int dd = idx >> 6, kk = idx & 63;
            WT[(size_t)(d0+dd)*2048 + k0 + kk] = (_Float16)s[kk*65 + dd];
        }
    } else if (bid < 2560) {
        // ---- Wb[49152][97] fp32 -> Wbt[768][128 c][64 j] half ----
        int kbi = bid - 1792;
        float* s = (float*)smem_raw;                   // [64*97]
        size_t gbase = (size_t)kbi * 64 * NC_;
        #pragma unroll
        for (int u = 0; u < 25; ++u) {
            int idx = t + u*256;
            if (idx < 64*NC_) s[idx] = Wb[gbase + idx];
        }
        __syncthreads();
        _Float16* dst = Wbt + (size_t)kbi * 8192;
        #pragma unroll
        for (int u = 0; u < 32; ++u) {
            int idx = t + u*256;
            int c = idx >> 6, j = idx & 63;
            float v = (c < NC_) ? s[j*NC_ + c] : 0.f;
            dst[idx] = (_Float16)v;
        }
    } else if (bid < 2816) {
        // ---- mention -> entity logsumexp pooling (half out) ----
        int blk = bid - 2560;
        int b = blk >> 6, e = blk & 63;
        int* lbl = (int*)smem_raw;
        if (t < M_) lbl[t] = labels[b*M_ + t];
        __syncthreads();
        const float* src = ent_lhs + (size_t)b * M_ * H_;
        float mx[4], sm[4];
        #pragma unroll
        for (int j = 0; j < 4; ++j) { mx[j] = -INFINITY; sm[j] = 0.f; }
        int cnt = 0;
        for (int m = 0; m < M_; ++m) {
            if (lbl[m] != e) continue;
            ++cnt;
            const float* row = src + m * H_;
            #pragma unroll
            for (int j = 0; j < 4; ++j) {
                float x = row[t + j*256];
                if (x > mx[j]) { sm[j] = sm[j] * __expf(mx[j] - x) + 1.f; mx[j] = x; }
                else           { sm[j] += __expf(x - mx[j]); }
            }
        }
        _Float16* dst = enth + (size_t)blk * H_;
        #pragma unroll
        for (int j = 0; j < 4; ++j)
            dst[t + j*256] = (_Float16)((cnt > 0) ? (mx[j] + __logf(sm[j])) : 0.f);
    } else if (bid < 3072) {
        // ---- mention -> entity mean attention, transposed half [b][e][l][nh] ----
        int blk = bid - 2816;
        int b = blk >> 6, e = blk & 63;
        int* lbl = (int*)smem_raw;
        if (t < M_) lbl[t] = labels[b*M_ + t];
        __syncthreads();
        const float* src = attn + (size_t)b * NH_ * M_ * L_;
        float acc[16][4] = {};
        int cnt = 0;
        for (int m = 0; m < M_; ++m) {
            if (lbl[m] != e) continue;
            ++cnt;
            const float* mp = src + (size_t)m * L_ + t*4;
            #pragma unroll
            for (int nh = 0; nh < 16; ++nh) {
                float4 v = *(const float4*)(mp + (size_t)nh * M_ * L_);
                acc[nh][0] += v.x; acc[nh][1] += v.y; acc[nh][2] += v.z; acc[nh][3] += v.w;
            }
        }
        float inv = 1.f / fmaxf((float)cnt, 1.f);
        _Float16* dst = ea_t + (size_t)blk * L_ * 16;
        #pragma unroll
        for (int j = 0; j < 4; ++j) {
            int l = t*4 + j;
            half8 o0, o1;
            #pragma unroll
            for (int nh = 0; nh < 8; ++nh) { o0[nh] = (_Float16)(acc[nh][j]*inv); o1[nh] = (_Float16)(acc[nh+8][j]*inv); }
            *(half8*)(dst + (size_t)l*16)     = o0;
            *(half8*)(dst + (size_t)l*16 + 8) = o1;
        }
    } else {
        int idx = (bid - 3072)*256 + t;
        if (idx < NPAIR_) sv[idx] = 0.f;
    }
}

// ------- per-pair attn product + fused rowsum: vh[n][l]; sv[n] += partial -------
__global__ __launch_bounds__(256) void k_ht(const _Float16* __restrict__ ea_t,
                                            const int* __restrict__ hts,
                                            _Float16* __restrict__ vh,
                                            float* __restrict__ sv) {
    int blk = blockIdx.x;            // b*64 + lc
    int b = blk >> 6, lc = blk & 63;
    int l0 = lc * LC_;
    __shared__ _Float16 tile[64*256];
    int t = threadIdx.x;
    {
        int e = t >> 2, part = t & 3;
        const _Float16* src = ea_t + ((size_t)(b*64 + e)*L_ + l0) * 16;
        #pragma unroll
        for (int u = 0; u < 8; ++u) {
            int unit = part*8 + u;
            int l = unit >> 1, nhh = unit & 1;
            half8 v = *(const half8*)(src + l*16 + nhh*8);
            *(half8*)&tile[e*256 + ((l ^ (e & 15))*16) + nhh*8] = v;
        }
    }
    __syncthreads();
    const int* hp = hts + b * R_ * 2;
    #pragma unroll
    for (int pp = 0; pp < 2; ++pp) {
        int p = pp*256 + t;
        int he = hp[p*2], te = hp[p*2 + 1];
        const _Float16* ha = &tile[he*256];
        const _Float16* ta = &tile[te*256];
        float accl[LC_];
        float psum = 0.f;
        #pragma unroll
        for (int l = 0; l < LC_; ++l) {
            half8 h0 = *(const half8*)&ha[((l ^ (he & 15))*16)];
            half8 h1 = *(const half8*)&ha[((l ^ (he & 15))*16) + 8];
            half8 t0 = *(const half8*)&ta[((l ^ (te & 15))*16)];
            half8 t1 = *(const half8*)&ta[((l ^ (te & 15))*16) + 8];
            float s = 0.f;
            #pragma unroll
            for (int q = 0; q < 8; ++q)
                s += (float)h0[q]*(float)t0[q] + (float)h1[q]*(float)t1[q];
            accl[l] = s;
            psum += s;
        }
        half8 o0, o1;
        #pragma unroll
        for (int q = 0; q < 8; ++q) { o0[q] = (_Float16)accl[q]; o1[q] = (_Float16)accl[q+8]; }
        _Float16* dst = vh + (size_t)(b*R_ + p)*L_ + l0;
        *(half8*)dst = o0;
        *(half8*)(dst + 8) = o1;
        atomicAdd(&sv[b*R_ + p], psum);
    }
}

// ------- rel (MFMA 128x64 tiles): relh[n][d] = invs[n] * sum_l vh[n][l] seqT[b][d][l] -------
__global__ __launch_bounds__(256) void k_relmm(const _Float16* __restrict__ vh,
                                               const _Float16* __restrict__ seqT,
                                               const float* __restrict__ sv,
                                               _Float16* __restrict__ relh) {
    const int nt = blockIdx.x;
    const int mt = blockIdx.y;
    const int b  = mt >> 2;
    __shared__ _Float16 As[2][128*64];
    __shared__ _Float16 Bs[2][64*64];
    const int t = threadIdx.x;
    const int w = t >> 6, lane = t & 63;
    const int r = lane & 15, g = lane >> 4;
    const int wm = w >> 1, wn = w & 1;
    const int srow = lane >> 3, scol = ((lane & 7) ^ srow) * 8;

    const _Float16* Ab = vh + (size_t)mt*128*1024;
    const _Float16* Bb = seqT + ((size_t)b*1024 + nt*64)*1024;

    #pragma unroll
    for (int cc = 0; cc < 6; ++cc) {
        int c = w*6 + cc;
        if (c < 16) gload_lds16(Ab + (size_t)(c*8 + srow)*1024 + scol, &As[0][c*512]);
        else        gload_lds16(Bb + (size_t)((c-16)*8 + srow)*1024 + scol, &Bs[0][(c-16)*512]);
    }
    f32x4 acc[4][2] = {};
    __syncthreads();

    for (int k = 0; k < 16; ++k) {
        const int cur = k & 1;
        if (k < 15) {
            const int k0 = (k+1)*64;
            #pragma unroll
            for (int cc = 0; cc < 6; ++cc) {
                int c = w*6 + cc;
                if (c < 16) gload_lds16(Ab + (size_t)(c*8 + srow)*1024 + k0 + scol, &As[cur^1][c*512]);
                else        gload_lds16(Bb + (size_t)((c-16)*8 + srow)*1024 + k0 + scol, &Bs[cur^1][(c-16)*512]);
            }
        }
        half8 aF[4][2], bF[2][2];
        #pragma unroll
        for (int mf = 0; mf < 4; ++mf) {
            int row = wm*64 + mf*16 + r;
            aF[mf][0] = *(const half8*)&As[cur][row*64 + ((g ^ (r&7))*8)];
            aF[mf][1] = *(const half8*)&As[cur][row*64 + (((4+g) ^ (r&7))*8)];
        }
        #pragma unroll
        for (int nf = 0; nf < 2; ++nf) {
            int row = wn*32 + nf*16 + r;
            bF[nf][0] = *(const half8*)&Bs[cur][row*64 + ((g ^ (r&7))*8)];
            bF[nf][1] = *(const half8*)&Bs[cur][row*64 + (((4+g) ^ (r&7))*8)];
        }
        #pragma unroll
        for (int mf = 0; mf < 4; ++mf)
            #pragma unroll
            for (int nf = 0; nf < 2; ++nf) {
                acc[mf][nf] = __builtin_amdgcn_mfma_f32_16x16x32_f16(aF[mf][0], bF[nf][0], acc[mf][nf], 0, 0, 0);
                acc[mf][nf] = __builtin_amdgcn_mfma_f32_16x16x32_f16(aF[mf][1], bF[nf][1], acc[mf][nf], 0, 0, 0);
            }
        __syncthreads();
    }
    #pragma unroll
    for (int mf = 0; mf < 4; ++mf) {
        int nb = mt*128 + wm*64 + mf*16 + g*4;
        float invs[4];
        #pragma unroll
        for (int q = 0; q < 4; ++q) invs[q] = 1.f / (sv[nb + q] + 1.6e-4f);
        #pragma unroll
        for (int nf = 0; nf < 2; ++nf) {
            int d = nt*64 + wn*32 + nf*16 + r;
            #pragma unroll
            for (int q = 0; q < 4; ++q)
                relh[(size_t)(nb + q)*1024 + d] = (_Float16)(acc[mf][nf][q] * invs[q]);
        }
    }
}

// ------- big GEMM (128x128 tiles): G = [relh;enth] @ [rel|ent halves of Wh,Wt] -------
__global__ __launch_bounds__(256) void k_bigmm(const _Float16* __restrict__ relh,
                                               const _Float16* __restrict__ enth,
                                               const _Float16* __restrict__ WhT,
                                               const _Float16* __restrict__ WtT,
                                               _Float16* __restrict__ G) {
    const int nt = blockIdx.x;
    const int mt = blockIdx.y;
    __shared__ _Float16 As[2][128*64];
    __shared__ _Float16 Bs[2][128*64];
    const int t = threadIdx.x;
    const int w = t >> 6, lane = t & 63;
    const int r = lane & 15, g = lane >> 4;
    const int wm = w >> 1, wn = w & 1;
    const int srow = lane >> 3, scol = ((lane & 7) ^ srow) * 8;

    const _Float16* Ab = (mt < 16) ? (relh + (size_t)mt*128*1024)
                                   : (enth + (size_t)(mt-16)*128*1024);
    const int koff = (mt < 16) ? 1024 : 0;
    const _Float16* Bb = ((nt < 6) ? (WhT + (size_t)nt*128*2048)
                                   : (WtT + (size_t)(nt-6)*128*2048)) + koff;

    #pragma unroll
    for (int cc = 0; cc < 4; ++cc) {
        int c = w*4 + cc;
        gload_lds16(Ab + (size_t)(c*8 + srow)*1024 + scol, &As[0][c*512]);
        gload_lds16(Bb + (size_t)(c*8 + srow)*2048 + scol, &Bs[0][c*512]);
    }
    f32x4 acc[4][4] = {};
    __syncthreads();

    for (int k = 0; k < 16; ++k) {
        const int cur = k & 1;
        if (k < 15) {
            const int k0 = (k+1)*64;
            #pragma unroll
            for (int cc = 0; cc < 4; ++cc) {
                int c = w*4 + cc;
                gload_lds16(Ab + (size_t)(c*8 + srow)*1024 + k0 + scol, &As[cur^1][c*512]);
                gload_lds16(Bb + (size_t)(c*8 + srow)*2048 + k0 + scol, &Bs[cur^1][c*512]);
            }
        }
        half8 aF[4][2], bF[4][2];
        #pragma unroll
        for (int mf = 0; mf < 4; ++mf) {
            int row = wm*64 + mf*16 + r;
            aF[mf][0] = *(const half8*)&As[cur][row*64 + ((g ^ (r&7))*8)];
            aF[mf][1] = *(const half8*)&As[cur][row*64 + (((4+g) ^ (r&7))*8)];
        }
        #pragma unroll
        for (int nf = 0; nf < 4; ++nf) {
            int row = wn*64 + nf*16 + r;
            bF[nf][0] = *(const half8*)&Bs[cur][row*64 + ((g ^ (r&7))*8)];
            bF[nf][1] = *(const half8*)&Bs[cur][row*64 + (((4+g) ^ (r&7))*8)];
        }
        #pragma unroll
        for (int mf = 0; mf < 4; ++mf)
            #pragma unroll
            for (int nf = 0; nf < 4; ++nf) {
                acc[mf][nf] = __builtin_amdgcn_mfma_f32_16x16x32_f16(aF[mf][0], bF[nf][0], acc[mf][nf], 0, 0, 0);
                acc[mf][nf] = __builtin_amdgcn_mfma_f32_16x16x32_f16(aF[mf][1], bF[nf][1], acc[mf][nf], 0, 0, 0);
            }
        __syncthreads();
    }
    #pragma unroll
    for (int mf = 0; mf < 4; ++mf) {
        int nrow = mt*128 + wm*64 + mf*16 + g*4;
        #pragma unroll
        for (int nf = 0; nf < 4; ++nf) {
            int v = nt*128 + wn*64 + nf*16 + r;
            #pragma unroll
            for (int q = 0; q < 4; ++q)
                G[(size_t)(nrow + q)*1536 + v] = (_Float16)acc[mf][nf][q];
        }
    }
}

// ------- combine: hsf/tsf = tanh(relW + gather(entW) + bias), all from G -------
__global__ __launch_bounds__(192) void k_combine(const _Float16* __restrict__ G,
                                                 const int* __restrict__ hts,
                                                 const float* __restrict__ bh,
                                                 const float* __restrict__ bt,
                                                 _Float16* __restrict__ hsf,
                                                 _Float16* __restrict__ tsf) {
    int n = blockIdx.x;
    int b = n >> 9;
    int t = threadIdx.x;
    int side = t / 96, u = t % 96;
    int d0 = u*8;
    int idx = hts[n*2 + side];
    const _Float16* grel = G + (size_t)n*1536 + side*768 + d0;
    const _Float16* gent = G + (size_t)(2048 + b*64 + idx)*1536 + side*768 + d0;
    const float* bias = side ? bt : bh;
    half8 a = *(const half8*)grel;
    half8 e = *(const half8*)gent;
    half8 o;
    #pragma unroll
    for (int q = 0; q < 8; ++q)
        o[q] = (_Float16)tanhf((float)a[q] + (float)e[q] + bias[d0+q]);
    _Float16* dst = (side ? tsf : hsf) + (size_t)n*EMB_ + d0;
    *(half8*)dst = o;
}

// ------- classifier (MFMA): partial[kb][n][c]; waves split by class; B global->reg -------
__global__ __launch_bounds__(256) void k_cls_mfma(const _Float16* __restrict__ hsf,
                                                  const _Float16* __restrict__ tsf,
                                                  const _Float16* __restrict__ Wbt,
                                                  float* __restrict__ partial) {
    const int kb = blockIdx.x;
    const int n0 = blockIdx.y * 128;
    const int t = threadIdx.x;
    const int w = t >> 6, lane = t & 63;
    const int r = lane & 15, g = lane >> 4;
    __shared__ _Float16 hs_s[128*72];

    {
        int n = t & 127, hh = t >> 7;
        const _Float16* src = &hsf[(size_t)(n0+n)*EMB_ + kb*64 + hh*32];
        #pragma unroll
        for (int u = 0; u < 4; ++u)
            *(half8*)&hs_s[n*72 + hh*32 + u*8] = *(const half8*)(src + u*8);
    }
    half8 tsF[8][2];
    #pragma unroll
    for (int nf = 0; nf < 8; ++nf) {
        const _Float16* tp = &tsf[(size_t)(n0 + nf*16 + r)*EMB_ + kb*64];
        tsF[nf][0] = *(const half8*)(tp + g*8);
        tsF[nf][1] = *(const half8*)(tp + 32 + g*8);
    }
    __syncthreads();

    const _Float16* wb = Wbt + (size_t)(kb*64) * 8192;
    f32x4 acc[8][2] = {};

    #pragma unroll 2
    for (int i = 0; i < 64; ++i) {
        const _Float16* ws_ = wb + (size_t)i * 8192;
        half8 b00, b01, b10, b11;
        {
            const _Float16* bp0 = ws_ + (size_t)(w*32 + r)*64;
            const _Float16* bp1 = ws_ + (size_t)(w*32 + 16 + r)*64;
            b00 = *(const half8*)(bp0 + g*8);
            b01 = *(const half8*)(bp0 + 32 + g*8);
            b10 = *(const half8*)(bp1 + g*8);
            b11 = *(const half8*)(bp1 + 32 + g*8);
        }
        #pragma unroll
        for (int nf = 0; nf < 8; ++nf) {
            _Float16 h = hs_s[(nf*16 + r)*72 + i];
            half8 a0, a1;
            #pragma unroll
            for (int e = 0; e < 8; ++e) { a0[e] = tsF[nf][0][e] * h; a1[e] = tsF[nf][1][e] * h; }
            acc[nf][0] = __builtin_amdgcn_mfma_f32_16x16x32_f16(a0, b00, acc[nf][0], 0, 0, 0);
            acc[nf][0] = __builtin_amdgcn_mfma_f32_16x16x32_f16(a1, b01, acc[nf][0], 0, 0, 0);
            acc[nf][1] = __builtin_amdgcn_mfma_f32_16x16x32_f16(a0, b10, acc[nf][1], 0, 0, 0);
            acc[nf][1] = __builtin_amdgcn_mfma_f32_16x16x32_f16(a1, b11, acc[nf][1], 0, 0, 0);
        }
    }
    float* pdst = partial + (size_t)kb * 2048 * 128;
    #pragma unroll
    for (int nf = 0; nf < 8; ++nf) {
        #pragma unroll
        for (int cl = 0; cl < 2; ++cl) {
            int c = w*32 + cl*16 + r;
            #pragma unroll
            for (int q = 0; q < 4; ++q)
                pdst[(size_t)(n0 + nf*16 + g*4 + q)*128 + c] = acc[nf][cl][q];
        }
    }
}

// ---------------- reduce partials + bias -> logits ----------------
__global__ __launch_bounds__(256) void k_reduce(const float* __restrict__ partial,
                                                const float* __restrict__ bb,
                                                float* __restrict__ out) {
    int idx = blockIdx.x*256 + threadIdx.x;
    if (idx >= NPAIR_*NC_) return;
    int n = idx / NC_, c = idx - n*NC_;
    float s = bb[c];
    #pragma unroll
    for (int kb = 0; kb < 12; ++kb)
        s += partial[((size_t)kb*2048 + n)*128 + c];
    out[idx] = s;
}

extern "C" void kernel_launch(void* const* d_in, const int* in_sizes, int n_in,
                              void* d_out, int out_size, void* d_ws, size_t ws_size,
                              hipStream_t stream) {
    (void)in_sizes; (void)n_in; (void)out_size; (void)ws_size;
    const float* seq  = (const float*)d_in[0];
    const float* ent  = (const float*)d_in[1];
    const float* attn = (const float*)d_in[2];
    const int*   lbl  = (const int*)d_in[3];
    const int*   hts  = (const int*)d_in[4];
    const float* Wh   = (const float*)d_in[5];
    const float* bh   = (const float*)d_in[6];
    const float* Wt   = (const float*)d_in[7];
    const float* bt   = (const float*)d_in[8];
    const float* Wb   = (const float*)d_in[9];
    const float* bb   = (const float*)d_in[10];
    float* out = (float*)d_out;
    float* ws  = (float*)d_ws;

    _Float16* ea_t = (_Float16*)(ws + OFF_EAT);
    _Float16* vh   = (_Float16*)(ws + OFF_VH);
    float*    part = ws + OFF_PART;
    _Float16* seqT = (_Float16*)(ws + OFF_SEQT);
    _Float16* G    = (_Float16*)(ws + OFF_G);
    _Float16* relh = (_Float16*)(ws + OFF_RELH);
    _Float16* Wbt  = (_Float16*)(ws + OFF_WBT);
    _Float16* enth = (_Float16*)(ws + OFF_ENTH);
    float*    sv   = ws + OFF_SV;
    _Float16* WhT  = (_Float16*)(ws + OFF_WHT);
    _Float16* WtT  = (_Float16*)(ws + OFF_WTT);
    _Float16* hsf  = (_Float16*)(ws + OFF_WHT);   // aliases WhT (dead after k_bigmm)
    _Float16* tsf  = (_Float16*)(ws + OFF_WTT);   // aliases WtT (dead after k_bigmm)

    k_prep_fused<<<3080, 256, 0, stream>>>(seq, Wh, Wt, Wb, ent, attn, lbl,
                                           seqT, WhT, WtT, Wbt, enth, ea_t, sv);
    k_ht<<<B_*64, 256, 0, stream>>>(ea_t, hts, vh, sv);
    k_relmm<<<dim3(16, 16), 256, 0, stream>>>(vh, seqT, sv, relh);
    k_bigmm<<<dim3(12, 18), 256, 0, stream>>>(relh, enth, WhT, WtT, G);   // overwrites seqT (dead)
    k_combine<<<NPAIR_, 192, 0, stream>>>(G, hts, bh, bt, hsf, tsf);      // overwrites WhT/WtT (dead)
    k_cls_mfma<<<dim3(12, 16), 256, 0, stream>>>(hsf, tsf, Wbt, part);    // overwrites ea_t+vh (dead)
    k_reduce<<<(NPAIR_*NC_ + 255)/256, 256, 0, stream>>>(part, bb, out);
}